// Round 5
// baseline (1111.862 us; speedup 1.0000x reference)
//
#include <hip/hip_runtime.h>
#include <math.h>

// GCN(2 layers, N=32768, E=524288, d=128) -> 2-layer cross-attention
// transformer (B=32, M=1024, d=128, H=8, dh=16, dff=512).
// R5: (1) attention blocks own 256 queries -> K/V staged once per 256q
//     (4x less staging, kb/vb frags reused across q-tiles);
//     (2) GEMMs on mfma_f32_32x32x16_bf16 (half the LDS reads per FLOP),
//     64x128 tile; (3) K+V projections fused into one ncols=256 GEMM.

typedef __attribute__((ext_vector_type(8)))  short short8;   // 8 bf16 = 4 VGPRs
typedef __attribute__((ext_vector_type(4)))  float f32x4;
typedef __attribute__((ext_vector_type(16))) float f32x16;

__device__ __forceinline__ unsigned short f2bf(float x) {   // RNE fp32->bf16
    unsigned u = __builtin_bit_cast(unsigned, x);
    u = (u + 0x7FFFu + ((u >> 16) & 1u)) >> 16;
    return (unsigned short)u;
}
__device__ __forceinline__ float bflo(unsigned u) { return __builtin_bit_cast(float, u << 16); }
__device__ __forceinline__ float bfhi(unsigned u) { return __builtin_bit_cast(float, u & 0xffff0000u); }

// ---------------------------------------------------------------------------
// CSR build
// ---------------------------------------------------------------------------
__global__ void count_kernel(const int* __restrict__ dst, int* __restrict__ cnt, int E) {
    int e = blockIdx.x * 256 + threadIdx.x;
    if (e < E) atomicAdd(&cnt[dst[e]], 1);
}

__global__ void dinv_kernel(const int* __restrict__ cnt, float* __restrict__ dinv, int N) {
    int i = blockIdx.x * 256 + threadIdx.x;
    if (i < N) dinv[i] = rsqrtf((float)cnt[i] + 1.0f);   // +1 self-loop
}

__global__ __launch_bounds__(1024)
void scan_kernel(const int* __restrict__ cnt, int* __restrict__ off,
                 int* __restrict__ cursor, int N)
{
    __shared__ int part[1024];
    const int t = threadIdx.x;
    int local[32];
    int s = 0;
    #pragma unroll
    for (int i = 0; i < 32; ++i) { local[i] = cnt[t * 32 + i]; s += local[i]; }
    part[t] = s;
    __syncthreads();
    int run = s;
    for (int o = 1; o < 1024; o <<= 1) {
        int v = (t >= o) ? part[t - o] : 0;
        __syncthreads();
        part[t] += v;
        __syncthreads();
    }
    int pre = part[t] - run;
    #pragma unroll
    for (int i = 0; i < 32; ++i) {
        off[t * 32 + i] = pre;
        cursor[t * 32 + i] = pre;
        pre += local[i];
    }
    if (t == 1023) off[N] = pre;
}

__global__ void place_kernel(const int* __restrict__ src, const int* __restrict__ dst,
                             int* __restrict__ cursor, int* __restrict__ csr_src, int E)
{
    int e = blockIdx.x * 256 + threadIdx.x;
    if (e < E) {
        int p = atomicAdd(&cursor[dst[e]], 1);
        csr_src[p] = src[e];
    }
}

// ---------------------------------------------------------------------------
// Conversions
// ---------------------------------------------------------------------------
__global__ void conv_kernel(const float* __restrict__ src, unsigned short* __restrict__ dst) {
    int i = blockIdx.x * 256 + threadIdx.x;
    float4 v = ((const float4*)src)[i];
    ushort4 h; h.x = f2bf(v.x); h.y = f2bf(v.y); h.z = f2bf(v.z); h.w = f2bf(v.w);
    ((ushort4*)dst)[i] = h;
}

__global__ void copyconv_kernel(const float* __restrict__ src, float* __restrict__ dstf,
                                unsigned short* __restrict__ dsth) {
    int i = blockIdx.x * 256 + threadIdx.x;
    float4 v = ((const float4*)src)[i];
    ((float4*)dstf)[i] = v;
    ushort4 h; h.x = f2bf(v.x); h.y = f2bf(v.y); h.z = f2bf(v.z); h.w = f2bf(v.w);
    ((ushort4*)dsth)[i] = h;
}

// ---------------------------------------------------------------------------
// Weight transpose+convert. K/V of each layer land as one 256-row matrix.
// ---------------------------------------------------------------------------
__global__ __launch_bounds__(256)
void wtrans_kernel(const float* Wg1, const float* Wg2, const float* Wq, const float* Wk,
                   const float* Wv, const float* Wo, const float* Wff1, const float* Wff2,
                   unsigned short* __restrict__ out)
{
    const int slot = blockIdx.y;
    const float* src; int ks; int Ns; size_t doff;
    if      (slot == 0)  { src = Wg1;                        ks = 7; Ns = 128; doff = 0; }
    else if (slot == 1)  { src = Wg2;                        ks = 7; Ns = 128; doff = 16384; }
    else if (slot <= 3)  { src = Wq  + (slot - 2)  * 16384;  ks = 7; Ns = 128; doff = 32768  + (size_t)(slot - 2)  * 16384; }
    else if (slot <= 5)  { src = Wk  + (slot - 4)  * 16384;  ks = 7; Ns = 128; doff = 65536  + (size_t)(slot - 4)  * 32768; }
    else if (slot <= 7)  { src = Wv  + (slot - 6)  * 16384;  ks = 7; Ns = 128; doff = 65536  + (size_t)(slot - 6)  * 32768 + 16384; }
    else if (slot <= 9)  { src = Wo  + (slot - 8)  * 16384;  ks = 7; Ns = 128; doff = 131072 + (size_t)(slot - 8)  * 16384; }
    else if (slot <= 11) { src = Wff1 + (slot - 10) * 65536; ks = 7; Ns = 512; doff = 163840 + (size_t)(slot - 10) * 65536; }
    else                 { src = Wff2 + (slot - 12) * 65536; ks = 9; Ns = 128; doff = 294912 + (size_t)(slot - 12) * 65536; }
    const int total = Ns << ks;
    int id = blockIdx.x * 256 + threadIdx.x;
    if (id >= total) return;
    int n = id >> ks;
    int k = id & ((1 << ks) - 1);
    out[doff + id] = f2bf(src[(size_t)k * Ns + n]);
}

// ---------------------------------------------------------------------------
// MFMA GEMM on 32x32x16: C[M x ncols] = op(A @ W), A bf16 (M x K, row-major),
// Wt bf16 (ncols x K). Tile 64 rows x 128 cols, BK=32, 4 waves:
// wave (w&1) -> 32-row half, (w>>1) -> 64-col half; each wave 2 32x32 tiles.
// A/B frag: m/n = lane&31, k = (lane>>5)*8 + j.  C/D: col=lane&31,
// row=(reg&3)+8*(reg>>2)+4*(lane>>5)  [verified mapping].
// ---------------------------------------------------------------------------
__global__ __launch_bounds__(256)
void gemm_mfma_kernel(const unsigned short* __restrict__ A,
                      const unsigned short* __restrict__ Wt,
                      void* __restrict__ C, int K, int ncols,
                      const float* __restrict__ bias, const float* __restrict__ rowscale,
                      int relu, int out_bf16)
{
    __shared__ unsigned short As[64 * 36];    // [row][k], stride 36 shorts (72B)
    __shared__ unsigned short Ws[128 * 36];   // [col][k]

    const int tid  = threadIdx.x;
    const int lane = tid & 63, wave = tid >> 6;
    const int m31 = lane & 31, hi = lane >> 5;
    const int row0 = blockIdx.x * 64;
    const int c0   = blockIdx.y * 128;
    const int wrow = (wave & 1) * 32;
    const int wcol = (wave >> 1) * 64;

    const int sr = tid >> 2;            // staging row/col 0..63
    const int sk = (tid & 3) * 8;       // k-offset 0,8,16,24

    f32x16 acc0 = {};
    f32x16 acc1 = {};

    for (int kt = 0; kt < K; kt += 32) {
        __syncthreads();
        *(short8*)&As[sr * 36 + sk] = *(const short8*)&A[(size_t)(row0 + sr) * K + kt + sk];
        #pragma unroll
        for (int p = 0; p < 2; ++p) {
            *(short8*)&Ws[(p * 64 + sr) * 36 + sk] =
                *(const short8*)&Wt[(size_t)(c0 + p * 64 + sr) * K + kt + sk];
        }
        __syncthreads();
        #pragma unroll
        for (int ks = 0; ks < 2; ++ks) {
            short8 af = *(const short8*)&As[(wrow + m31) * 36 + ks * 16 + hi * 8];
            short8 b0 = *(const short8*)&Ws[(wcol + m31) * 36 + ks * 16 + hi * 8];
            short8 b1 = *(const short8*)&Ws[(wcol + 32 + m31) * 36 + ks * 16 + hi * 8];
            acc0 = __builtin_amdgcn_mfma_f32_32x32x16_bf16(af, b0, acc0, 0, 0, 0);
            acc1 = __builtin_amdgcn_mfma_f32_32x32x16_bf16(af, b1, acc1, 0, 0, 0);
        }
    }

    #pragma unroll
    for (int r = 0; r < 16; ++r) {
        const int row = row0 + wrow + (r & 3) + 8 * (r >> 2) + 4 * hi;
        const float rs = rowscale ? rowscale[row] : 1.0f;
        #pragma unroll
        for (int ct = 0; ct < 2; ++ct) {
            const int col = c0 + wcol + ct * 32 + m31;
            float v = (ct ? acc1[r] : acc0[r]) * rs;
            if (bias) v += bias[col];
            if (relu) v = fmaxf(v, 0.0f);
            size_t off = (size_t)row * ncols + col;
            if (out_bf16) ((unsigned short*)C)[off] = f2bf(v);
            else          ((float*)C)[off] = v;
        }
    }
}

// ---------------------------------------------------------------------------
// GCN gather (bf16 in/out): one wave per node, 2 channels per lane.
// ---------------------------------------------------------------------------
__global__ __launch_bounds__(256)
void gather_kernel(const unsigned short* __restrict__ hs, const int* __restrict__ csr_off,
                   const int* __restrict__ csr_src, const float* __restrict__ dinv,
                   const float* __restrict__ bias, unsigned short* __restrict__ out, int N)
{
    const int node = blockIdx.x * 4 + (threadIdx.x >> 6);
    const int lane = threadIdx.x & 63;
    const int s0 = csr_off[node], s1 = csr_off[node + 1];
    const unsigned* hsu = (const unsigned*)hs;

    unsigned u = hsu[(size_t)node * 64 + lane];
    float a0 = bflo(u), a1 = bfhi(u);

    for (int base = s0; base < s1; base += 64) {
        int cnt = s1 - base; if (cnt > 64) cnt = 64;
        int idx = (base + lane < s1) ? csr_src[base + lane] : 0;
        int j = 0;
        for (; j + 4 <= cnt; j += 4) {
            size_t sA = (size_t)__shfl(idx, j,     64) * 64;
            size_t sB = (size_t)__shfl(idx, j + 1, 64) * 64;
            size_t sC = (size_t)__shfl(idx, j + 2, 64) * 64;
            size_t sD = (size_t)__shfl(idx, j + 3, 64) * 64;
            unsigned uA = hsu[sA + lane], uB = hsu[sB + lane];
            unsigned uC = hsu[sC + lane], uD = hsu[sD + lane];
            a0 += (bflo(uA) + bflo(uB)) + (bflo(uC) + bflo(uD));
            a1 += (bfhi(uA) + bfhi(uB)) + (bfhi(uC) + bfhi(uD));
        }
        for (; j < cnt; ++j) {
            size_t sb = (size_t)__shfl(idx, j, 64) * 64;
            unsigned ub = hsu[sb + lane];
            a0 += bflo(ub); a1 += bfhi(ub);
        }
    }
    float di = dinv[node];
    float v0 = fmaxf(a0 * di + bias[lane * 2],     0.0f);
    float v1 = fmaxf(a1 * di + bias[lane * 2 + 1], 0.0f);
    ((unsigned*)out)[(size_t)node * 64 + lane] =
        ((unsigned)f2bf(v1) << 16) | (unsigned)f2bf(v0);
}

// ---------------------------------------------------------------------------
// MFMA flash cross-attention. Block = (256-q group, head, batch), 4 waves;
// wave owns 64 q (4 16-row tiles). K/V staged in 256-key chunks from the
// fused KV buffer ([row][256]: cols 0-127 K, 128-255 V); kb/vb fragments
// reused across the wave's 4 q-tiles. No-max softmax, deferred l.
// ---------------------------------------------------------------------------
__global__ __launch_bounds__(256, 4)
void attn_mfma_kernel(const unsigned short* __restrict__ Qh,
                      const unsigned short* __restrict__ KVh,
                      unsigned short* __restrict__ Obh)
{
    __shared__ unsigned short Ks[256 * 40];    // [key][dim 0..31 padded]
    __shared__ unsigned short Vt[16 * 264];    // [dim][key'] (256 permuted keys)
    __shared__ unsigned short Ps[4][16 * 72];  // per-wave [q][key' within sub]

    const int tid  = threadIdx.x;
    const int lane = tid & 63, wave = tid >> 6;
    const int quad = lane >> 4, l16 = lane & 15;
    const int q0 = blockIdx.x * 256, h = blockIdx.y, b = blockIdx.z;

    {   // zero K dim-pad (dims 16..31) for all 256 rows, once
        short8 z = {};
        *(short8*)&Ks[tid * 40 + 16] = z;
        *(short8*)&Ks[tid * 40 + 24] = z;
    }

    short8 qa[4] = {};
    if (quad < 2) {
        #pragma unroll
        for (int qt = 0; qt < 4; ++qt)
            qa[qt] = *(const short8*)&Qh[((size_t)b * 1024 + q0 + wave * 64 + qt * 16 + l16) * 128 + h * 16 + quad * 8];
    }

    f32x4 o[4] = {};
    float l0[4][4] = {};
    unsigned short* Pw = &Ps[wave][0];
    const size_t kvbase = ((size_t)b * 1024) * 256 + (size_t)h * 16;

    for (int c = 0; c < 4; ++c) {
        __syncthreads();
        {   // stage 256 keys: K rows + V transposed (per-sub permuted cols)
            const int kk = tid;
            size_t g = kvbase + (size_t)(c * 256 + kk) * 256;
            *(short8*)&Ks[kk * 40]     = *(const short8*)&KVh[g];
            *(short8*)&Ks[kk * 40 + 8] = *(const short8*)&KVh[g + 8];
            ushort4 v0 = *(const ushort4*)&KVh[g + 128];
            ushort4 v1 = *(const ushort4*)&KVh[g + 132];
            ushort4 v2 = *(const ushort4*)&KVh[g + 136];
            ushort4 v3 = *(const ushort4*)&KVh[g + 140];
            int col2 = (kk >> 6) * 64 + (kk & 15) * 4 + ((kk >> 4) & 3);
            Vt[ 0 * 264 + col2] = v0.x; Vt[ 1 * 264 + col2] = v0.y;
            Vt[ 2 * 264 + col2] = v0.z; Vt[ 3 * 264 + col2] = v0.w;
            Vt[ 4 * 264 + col2] = v1.x; Vt[ 5 * 264 + col2] = v1.y;
            Vt[ 6 * 264 + col2] = v1.z; Vt[ 7 * 264 + col2] = v1.w;
            Vt[ 8 * 264 + col2] = v2.x; Vt[ 9 * 264 + col2] = v2.y;
            Vt[10 * 264 + col2] = v2.z; Vt[11 * 264 + col2] = v2.w;
            Vt[12 * 264 + col2] = v3.x; Vt[13 * 264 + col2] = v3.y;
            Vt[14 * 264 + col2] = v3.z; Vt[15 * 264 + col2] = v3.w;
        }
        __syncthreads();

        #pragma unroll
        for (int sub = 0; sub < 4; ++sub) {
            // shared fragments for this 64-key subchunk (reused by all 4 q-tiles)
            short8 kb0 = *(const short8*)&Ks[(sub * 64 +  0 + l16) * 40 + quad * 8];
            short8 kb1 = *(const short8*)&Ks[(sub * 64 + 16 + l16) * 40 + quad * 8];
            short8 kb2 = *(const short8*)&Ks[(sub * 64 + 32 + l16) * 40 + quad * 8];
            short8 kb3 = *(const short8*)&Ks[(sub * 64 + 48 + l16) * 40 + quad * 8];
            short8 vb0 = *(const short8*)&Vt[l16 * 264 + sub * 64 + quad * 8];
            short8 vb1 = *(const short8*)&Vt[l16 * 264 + sub * 64 + 32 + quad * 8];

            #pragma unroll
            for (int qt = 0; qt < 4; ++qt) {
                f32x4 zc = {0.f, 0.f, 0.f, 0.f};
                f32x4 s0 = __builtin_amdgcn_mfma_f32_16x16x32_bf16(qa[qt], kb0, zc, 0, 0, 0);
                f32x4 s1 = __builtin_amdgcn_mfma_f32_16x16x32_bf16(qa[qt], kb1, zc, 0, 0, 0);
                f32x4 s2 = __builtin_amdgcn_mfma_f32_16x16x32_bf16(qa[qt], kb2, zc, 0, 0, 0);
                f32x4 s3 = __builtin_amdgcn_mfma_f32_16x16x32_bf16(qa[qt], kb3, zc, 0, 0, 0);
                #pragma unroll
                for (int r = 0; r < 4; ++r) {
                    float p0 = __expf(s0[r] * 0.25f);
                    float p1 = __expf(s1[r] * 0.25f);
                    float p2 = __expf(s2[r] * 0.25f);
                    float p3 = __expf(s3[r] * 0.25f);
                    l0[qt][r] += (p0 + p1) + (p2 + p3);
                    unsigned q01 = __builtin_amdgcn_perm(__builtin_bit_cast(unsigned, p1),
                                                         __builtin_bit_cast(unsigned, p0), 0x07060302u);
                    unsigned q23 = __builtin_amdgcn_perm(__builtin_bit_cast(unsigned, p3),
                                                         __builtin_bit_cast(unsigned, p2), 0x07060302u);
                    uint2 pk; pk.x = q01; pk.y = q23;
                    *(uint2*)&Pw[(quad * 4 + r) * 72 + l16 * 4] = pk;
                }
                asm volatile("s_waitcnt lgkmcnt(0)" ::: "memory");
                short8 pa0 = *(const short8*)&Pw[l16 * 72 + quad * 8];
                short8 pa1 = *(const short8*)&Pw[l16 * 72 + 32 + quad * 8];
                o[qt] = __builtin_amdgcn_mfma_f32_16x16x32_bf16(pa0, vb0, o[qt], 0, 0, 0);
                o[qt] = __builtin_amdgcn_mfma_f32_16x16x32_bf16(pa1, vb1, o[qt], 0, 0, 0);
            }
        }
    }

    #pragma unroll
    for (int qt = 0; qt < 4; ++qt) {
        #pragma unroll
        for (int r = 0; r < 4; ++r) {
            float lr = l0[qt][r];
            #pragma unroll
            for (int off = 1; off < 16; off <<= 1) lr += __shfl_xor(lr, off, 64);
            float linv = 1.0f / lr;
            int qrow = q0 + wave * 64 + qt * 16 + quad * 4 + r;
            Obh[((size_t)b * 1024 + qrow) * 128 + h * 16 + l16] = f2bf(o[qt][r] * linv);
        }
    }
}

// ---------------------------------------------------------------------------
// y = LN(y + t) * g + b; writes f32 master and bf16 shadow
// ---------------------------------------------------------------------------
__global__ __launch_bounds__(256)
void resid_ln_kernel(float* __restrict__ y, const float* __restrict__ t,
                     const float* __restrict__ g, const float* __restrict__ bb,
                     unsigned short* __restrict__ yh)
{
    int r = blockIdx.x * 4 + (threadIdx.x >> 6);
    int lane = threadIdx.x & 63;
    size_t base = (size_t)r * 128;
    float v0 = y[base + lane]      + t[base + lane];
    float v1 = y[base + 64 + lane] + t[base + 64 + lane];
    float s = v0 + v1;
    #pragma unroll
    for (int off = 32; off; off >>= 1) s += __shfl_xor(s, off, 64);
    float mu = s * (1.0f / 128.0f);
    float d0 = v0 - mu, d1 = v1 - mu;
    float q = d0 * d0 + d1 * d1;
    #pragma unroll
    for (int off = 32; off; off >>= 1) q += __shfl_xor(q, off, 64);
    float inv = rsqrtf(q * (1.0f / 128.0f) + 1e-5f);
    float o0 = d0 * inv * g[lane]      + bb[lane];
    float o1 = d1 * inv * g[lane + 64] + bb[lane + 64];
    y[base + lane]      = o0;
    y[base + 64 + lane] = o1;
    yh[base + lane]      = f2bf(o0);
    yh[base + 64 + lane] = f2bf(o1);
}

// ---------------------------------------------------------------------------
extern "C" void kernel_launch(void* const* d_in, const int* in_sizes, int n_in,
                              void* d_out, int out_size, void* d_ws, size_t ws_size,
                              hipStream_t stream)
{
    const float* enc  = (const float*)d_in[0];
    const float* xraw = (const float*)d_in[2];
    const int*   ei   = (const int*)d_in[3];
    const float* Wg1  = (const float*)d_in[4];
    const float* bg1  = (const float*)d_in[5];
    const float* Wg2  = (const float*)d_in[6];
    const float* bg2  = (const float*)d_in[7];
    const float* Wq   = (const float*)d_in[8];
    const float* Wk   = (const float*)d_in[9];
    const float* Wv   = (const float*)d_in[10];
    const float* Wo   = (const float*)d_in[11];
    const float* Wff1 = (const float*)d_in[12];
    const float* bff1 = (const float*)d_in[13];
    const float* Wff2 = (const float*)d_in[14];
    const float* bff2 = (const float*)d_in[15];
    const float* ln1g = (const float*)d_in[16];
    const float* ln1b = (const float*)d_in[17];
    const float* ln2g = (const float*)d_in[18];
    const float* ln2b = (const float*)d_in[19];

    const int E  = in_sizes[3] / 2;            // 524288
    const int N  = in_sizes[2] / 128;          // 32768
    const int BM = in_sizes[0] / 128;          // 32768
    const int B  = BM / 1024;                  // 32
    const int L  = in_sizes[8] / (128 * 128);  // 2

    const int* srcE = ei;
    const int* dstE = ei + E;

    const size_t ND = (size_t)N * 128;         // 4194304
    float* ws   = (float*)d_ws;
    float* dinv = ws;                          // N f32
    float* bufY = ws + 32768;                  // ND f32 (residual master)
    float* bufA = bufY + ND;                   // ND f32 (pre-LN temp)
    unsigned short* ush   = (unsigned short*)(bufA + ND);
    unsigned short* bufYh = ush;               // ND bf16 (residual shadow)
    unsigned short* xrawh = bufYh + ND;        // ND
    unsigned short* hsh   = xrawh + ND;        // ND (GCN gemm out)
    unsigned short* bufBh = hsh + ND;          // ND (GCN features / KV src)
    unsigned short* region = bufBh + ND;       // 4*ND bf16
    unsigned short* Qh  = region;              // ND
    unsigned short* KVh = region + ND;         // 2*ND ([row][256]: K | V)
    unsigned short* Th  = region + 3 * ND;     // ND (attn out)
    unsigned short* Hh  = region;              // FFN hidden (4*ND), overlaps
    unsigned short* wt  = region + 4 * ND;     // 425984 bf16
    int* cnt     = (int*)(wt + 425984);        // N
    int* csr_off = cnt + N;                    // N+1
    int* cursor  = csr_off + N + 1;            // N
    int* csr_src = cursor + N;                 // E

    // --- CSR + dinv ---
    hipMemsetAsync(cnt, 0, (size_t)N * sizeof(int), stream);
    count_kernel<<<(E + 255) / 256, 256, 0, stream>>>(dstE, cnt, E);
    dinv_kernel<<<(N + 255) / 256, 256, 0, stream>>>(cnt, dinv, N);
    scan_kernel<<<1, 1024, 0, stream>>>(cnt, csr_off, cursor, N);
    place_kernel<<<(E + 255) / 256, 256, 0, stream>>>(srcE, dstE, cursor, csr_src, E);

    // --- converts + weight transpose ---
    conv_kernel<<<(int)(ND / 1024), 256, 0, stream>>>(xraw, xrawh);
    copyconv_kernel<<<(int)(ND / 1024), 256, 0, stream>>>(enc, bufY, bufYh);
    wtrans_kernel<<<dim3(256, 14), 256, 0, stream>>>(Wg1, Wg2, Wq, Wk, Wv, Wo, Wff1, Wff2, wt);

    // --- GCN layer 1 ---
    gemm_mfma_kernel<<<dim3(N / 64, 1), 256, 0, stream>>>(xrawh, wt, hsh, 128, 128, nullptr, dinv, 0, 1);
    gather_kernel<<<N / 4, 256, 0, stream>>>(hsh, csr_off, csr_src, dinv, bg1, bufBh, N);
    // --- GCN layer 2 ---
    gemm_mfma_kernel<<<dim3(N / 64, 1), 256, 0, stream>>>(bufBh, wt + 16384, hsh, 128, 128, nullptr, dinv, 0, 1);
    gather_kernel<<<N / 4, 256, 0, stream>>>(hsh, csr_off, csr_src, dinv, bg2, bufBh, N);
    // bufBh = GCN features (KV source)

    for (int l = 0; l < L; ++l) {
        const unsigned short* wtq  = wt + 32768  + (size_t)l * 16384;
        const unsigned short* wtkv = wt + 65536  + (size_t)l * 32768;
        const unsigned short* wto  = wt + 131072 + (size_t)l * 16384;
        const unsigned short* wtf1 = wt + 163840 + (size_t)l * 65536;
        const unsigned short* wtf2 = wt + 294912 + (size_t)l * 65536;

        gemm_mfma_kernel<<<dim3(BM / 64, 1), 256, 0, stream>>>(bufYh, wtq, Qh, 128, 128, nullptr, nullptr, 0, 1);
        gemm_mfma_kernel<<<dim3(N / 64, 2), 256, 0, stream>>>(bufBh, wtkv, KVh, 128, 256, nullptr, nullptr, 0, 1);

        attn_mfma_kernel<<<dim3(4, 8, B), 256, 0, stream>>>(Qh, KVh, Th);

        gemm_mfma_kernel<<<dim3(BM / 64, 1), 256, 0, stream>>>(Th, wto, bufA, 128, 128, nullptr, nullptr, 0, 0);
        resid_ln_kernel<<<BM / 4, 256, 0, stream>>>(bufY, bufA, ln1g + l * 128, ln1b + l * 128, bufYh);

        gemm_mfma_kernel<<<dim3(BM / 64, 4), 256, 0, stream>>>(bufYh, wtf1, Hh, 128, 512, bff1 + l * 512, nullptr, 1, 1);
        gemm_mfma_kernel<<<dim3(BM / 64, 1), 256, 0, stream>>>(Hh, wtf2, bufA, 512, 128, bff2 + l * 128, nullptr, 0, 0);
        resid_ln_kernel<<<BM / 4, 256, 0, stream>>>(bufY, bufA, ln2g + l * 128, ln2b + l * 128, bufYh);
    }

    hipMemcpyAsync(d_out, bufY, (size_t)out_size * sizeof(float), hipMemcpyDeviceToDevice, stream);
}

// Round 6
// 633.023 us; speedup vs baseline: 1.7564x; 1.7564x over previous
//
#include <hip/hip_runtime.h>
#include <math.h>

// GCN(2 layers, N=32768, E=524288, d=128) -> 2-layer cross-attention
// transformer (B=32, M=1024, d=128, H=8, dh=16, dff=512).
// R6: attention reverted to R4's spill-free shape (wave=16q, 64-key chunks,
// no occupancy clamp) reading the fused KV buffer; 1/sqrt(dh) folded into Wq.
// GEMM: 128x128 tile, wave=64x64 as 2x2 mfma_32x32x16 -> 1:1 LDS:MFMA ratio.

typedef __attribute__((ext_vector_type(8)))  short short8;   // 8 bf16 = 4 VGPRs
typedef __attribute__((ext_vector_type(4)))  float f32x4;
typedef __attribute__((ext_vector_type(16))) float f32x16;

__device__ __forceinline__ unsigned short f2bf(float x) {   // RNE fp32->bf16
    unsigned u = __builtin_bit_cast(unsigned, x);
    u = (u + 0x7FFFu + ((u >> 16) & 1u)) >> 16;
    return (unsigned short)u;
}
__device__ __forceinline__ float bflo(unsigned u) { return __builtin_bit_cast(float, u << 16); }
__device__ __forceinline__ float bfhi(unsigned u) { return __builtin_bit_cast(float, u & 0xffff0000u); }

// ---------------------------------------------------------------------------
// CSR build
// ---------------------------------------------------------------------------
__global__ void count_kernel(const int* __restrict__ dst, int* __restrict__ cnt, int E) {
    int e = blockIdx.x * 256 + threadIdx.x;
    if (e < E) atomicAdd(&cnt[dst[e]], 1);
}

__global__ void dinv_kernel(const int* __restrict__ cnt, float* __restrict__ dinv, int N) {
    int i = blockIdx.x * 256 + threadIdx.x;
    if (i < N) dinv[i] = rsqrtf((float)cnt[i] + 1.0f);   // +1 self-loop
}

__global__ __launch_bounds__(1024)
void scan_kernel(const int* __restrict__ cnt, int* __restrict__ off,
                 int* __restrict__ cursor, int N)
{
    __shared__ int part[1024];
    const int t = threadIdx.x;
    int local[32];
    int s = 0;
    #pragma unroll
    for (int i = 0; i < 32; ++i) { local[i] = cnt[t * 32 + i]; s += local[i]; }
    part[t] = s;
    __syncthreads();
    int run = s;
    for (int o = 1; o < 1024; o <<= 1) {
        int v = (t >= o) ? part[t - o] : 0;
        __syncthreads();
        part[t] += v;
        __syncthreads();
    }
    int pre = part[t] - run;
    #pragma unroll
    for (int i = 0; i < 32; ++i) {
        off[t * 32 + i] = pre;
        cursor[t * 32 + i] = pre;
        pre += local[i];
    }
    if (t == 1023) off[N] = pre;
}

__global__ void place_kernel(const int* __restrict__ src, const int* __restrict__ dst,
                             int* __restrict__ cursor, int* __restrict__ csr_src, int E)
{
    int e = blockIdx.x * 256 + threadIdx.x;
    if (e < E) {
        int p = atomicAdd(&cursor[dst[e]], 1);
        csr_src[p] = src[e];
    }
}

// ---------------------------------------------------------------------------
// Conversions
// ---------------------------------------------------------------------------
__global__ void conv_kernel(const float* __restrict__ src, unsigned short* __restrict__ dst) {
    int i = blockIdx.x * 256 + threadIdx.x;
    float4 v = ((const float4*)src)[i];
    ushort4 h; h.x = f2bf(v.x); h.y = f2bf(v.y); h.z = f2bf(v.z); h.w = f2bf(v.w);
    ((ushort4*)dst)[i] = h;
}

__global__ void copyconv_kernel(const float* __restrict__ src, float* __restrict__ dstf,
                                unsigned short* __restrict__ dsth) {
    int i = blockIdx.x * 256 + threadIdx.x;
    float4 v = ((const float4*)src)[i];
    ((float4*)dstf)[i] = v;
    ushort4 h; h.x = f2bf(v.x); h.y = f2bf(v.y); h.z = f2bf(v.z); h.w = f2bf(v.w);
    ((ushort4*)dsth)[i] = h;
}

// ---------------------------------------------------------------------------
// Weight transpose+convert. K/V of each layer land as one 256-row matrix.
// Wq is scaled by 0.25 (= 1/sqrt(dh)) so attention scores need no scale mul.
// ---------------------------------------------------------------------------
__global__ __launch_bounds__(256)
void wtrans_kernel(const float* Wg1, const float* Wg2, const float* Wq, const float* Wk,
                   const float* Wv, const float* Wo, const float* Wff1, const float* Wff2,
                   unsigned short* __restrict__ out)
{
    const int slot = blockIdx.y;
    const float* src; int ks; int Ns; size_t doff; float scale = 1.0f;
    if      (slot == 0)  { src = Wg1;                        ks = 7; Ns = 128; doff = 0; }
    else if (slot == 1)  { src = Wg2;                        ks = 7; Ns = 128; doff = 16384; }
    else if (slot <= 3)  { src = Wq  + (slot - 2)  * 16384;  ks = 7; Ns = 128; doff = 32768  + (size_t)(slot - 2)  * 16384; scale = 0.25f; }
    else if (slot <= 5)  { src = Wk  + (slot - 4)  * 16384;  ks = 7; Ns = 128; doff = 65536  + (size_t)(slot - 4)  * 32768; }
    else if (slot <= 7)  { src = Wv  + (slot - 6)  * 16384;  ks = 7; Ns = 128; doff = 65536  + (size_t)(slot - 6)  * 32768 + 16384; }
    else if (slot <= 9)  { src = Wo  + (slot - 8)  * 16384;  ks = 7; Ns = 128; doff = 131072 + (size_t)(slot - 8)  * 16384; }
    else if (slot <= 11) { src = Wff1 + (slot - 10) * 65536; ks = 7; Ns = 512; doff = 163840 + (size_t)(slot - 10) * 65536; }
    else                 { src = Wff2 + (slot - 12) * 65536; ks = 9; Ns = 128; doff = 294912 + (size_t)(slot - 12) * 65536; }
    const int total = Ns << ks;
    int id = blockIdx.x * 256 + threadIdx.x;
    if (id >= total) return;
    int n = id >> ks;
    int k = id & ((1 << ks) - 1);
    out[doff + id] = f2bf(src[(size_t)k * Ns + n] * scale);
}

// ---------------------------------------------------------------------------
// MFMA GEMM on 32x32x16: C[M x ncols] = op(A @ W), A bf16 (M x K, row-major),
// Wt bf16 (ncols x K). Tile 128 rows x 128 cols, BK=32, 4 waves; wave owns
// 64x64 as 2x2 32x32 tiles -> per ks-step 4 ds_read_b128 : 4 MFMA.
// C/D: col=lane&31, row=(reg&3)+8*(reg>>2)+4*(lane>>5)  [verified mapping].
// ---------------------------------------------------------------------------
__global__ __launch_bounds__(256)
void gemm_mfma_kernel(const unsigned short* __restrict__ A,
                      const unsigned short* __restrict__ Wt,
                      void* __restrict__ C, int K, int ncols,
                      const float* __restrict__ bias, const float* __restrict__ rowscale,
                      int relu, int out_bf16)
{
    __shared__ unsigned short As[128 * 36];   // [row][k], stride 36 shorts
    __shared__ unsigned short Ws[128 * 36];   // [col][k]

    const int tid  = threadIdx.x;
    const int lane = tid & 63, wave = tid >> 6;
    const int m31 = lane & 31, hi = lane >> 5;
    const int row0 = blockIdx.x * 128;
    const int c0   = blockIdx.y * 128;
    const int wrow = (wave & 1) * 64;
    const int wcol = (wave >> 1) * 64;

    const int sr = tid >> 1;            // staging row/col 0..127
    const int sk = (tid & 1) * 16;      // k-offset 0 or 16

    f32x16 acc00 = {}, acc01 = {}, acc10 = {}, acc11 = {};

    for (int kt = 0; kt < K; kt += 32) {
        __syncthreads();
        *(short8*)&As[sr * 36 + sk]     = *(const short8*)&A[(size_t)(row0 + sr) * K + kt + sk];
        *(short8*)&As[sr * 36 + sk + 8] = *(const short8*)&A[(size_t)(row0 + sr) * K + kt + sk + 8];
        *(short8*)&Ws[sr * 36 + sk]     = *(const short8*)&Wt[(size_t)(c0 + sr) * K + kt + sk];
        *(short8*)&Ws[sr * 36 + sk + 8] = *(const short8*)&Wt[(size_t)(c0 + sr) * K + kt + sk + 8];
        __syncthreads();
        #pragma unroll
        for (int ks = 0; ks < 2; ++ks) {
            short8 a0 = *(const short8*)&As[(wrow + m31) * 36 + ks * 16 + hi * 8];
            short8 a1 = *(const short8*)&As[(wrow + 32 + m31) * 36 + ks * 16 + hi * 8];
            short8 b0 = *(const short8*)&Ws[(wcol + m31) * 36 + ks * 16 + hi * 8];
            short8 b1 = *(const short8*)&Ws[(wcol + 32 + m31) * 36 + ks * 16 + hi * 8];
            acc00 = __builtin_amdgcn_mfma_f32_32x32x16_bf16(a0, b0, acc00, 0, 0, 0);
            acc01 = __builtin_amdgcn_mfma_f32_32x32x16_bf16(a0, b1, acc01, 0, 0, 0);
            acc10 = __builtin_amdgcn_mfma_f32_32x32x16_bf16(a1, b0, acc10, 0, 0, 0);
            acc11 = __builtin_amdgcn_mfma_f32_32x32x16_bf16(a1, b1, acc11, 0, 0, 0);
        }
    }

    #pragma unroll
    for (int rt = 0; rt < 2; ++rt) {
        #pragma unroll
        for (int r = 0; r < 16; ++r) {
            const int row = row0 + wrow + rt * 32 + (r & 3) + 8 * (r >> 2) + 4 * hi;
            const float rs = rowscale ? rowscale[row] : 1.0f;
            #pragma unroll
            for (int ct = 0; ct < 2; ++ct) {
                const int col = c0 + wcol + ct * 32 + m31;
                float v = (rt ? (ct ? acc11[r] : acc10[r]) : (ct ? acc01[r] : acc00[r])) * rs;
                if (bias) v += bias[col];
                if (relu) v = fmaxf(v, 0.0f);
                size_t off = (size_t)row * ncols + col;
                if (out_bf16) ((unsigned short*)C)[off] = f2bf(v);
                else          ((float*)C)[off] = v;
            }
        }
    }
}

// ---------------------------------------------------------------------------
// GCN gather (bf16 in/out): one wave per node, 2 channels per lane.
// ---------------------------------------------------------------------------
__global__ __launch_bounds__(256)
void gather_kernel(const unsigned short* __restrict__ hs, const int* __restrict__ csr_off,
                   const int* __restrict__ csr_src, const float* __restrict__ dinv,
                   const float* __restrict__ bias, unsigned short* __restrict__ out, int N)
{
    const int node = blockIdx.x * 4 + (threadIdx.x >> 6);
    const int lane = threadIdx.x & 63;
    const int s0 = csr_off[node], s1 = csr_off[node + 1];
    const unsigned* hsu = (const unsigned*)hs;

    unsigned u = hsu[(size_t)node * 64 + lane];
    float a0 = bflo(u), a1 = bfhi(u);

    for (int base = s0; base < s1; base += 64) {
        int cnt = s1 - base; if (cnt > 64) cnt = 64;
        int idx = (base + lane < s1) ? csr_src[base + lane] : 0;
        int j = 0;
        for (; j + 4 <= cnt; j += 4) {
            size_t sA = (size_t)__shfl(idx, j,     64) * 64;
            size_t sB = (size_t)__shfl(idx, j + 1, 64) * 64;
            size_t sC = (size_t)__shfl(idx, j + 2, 64) * 64;
            size_t sD = (size_t)__shfl(idx, j + 3, 64) * 64;
            unsigned uA = hsu[sA + lane], uB = hsu[sB + lane];
            unsigned uC = hsu[sC + lane], uD = hsu[sD + lane];
            a0 += (bflo(uA) + bflo(uB)) + (bflo(uC) + bflo(uD));
            a1 += (bfhi(uA) + bfhi(uB)) + (bfhi(uC) + bfhi(uD));
        }
        for (; j < cnt; ++j) {
            size_t sb = (size_t)__shfl(idx, j, 64) * 64;
            unsigned ub = hsu[sb + lane];
            a0 += bflo(ub); a1 += bfhi(ub);
        }
    }
    float di = dinv[node];
    float v0 = fmaxf(a0 * di + bias[lane * 2],     0.0f);
    float v1 = fmaxf(a1 * di + bias[lane * 2 + 1], 0.0f);
    ((unsigned*)out)[(size_t)node * 64 + lane] =
        ((unsigned)f2bf(v1) << 16) | (unsigned)f2bf(v0);
}

// ---------------------------------------------------------------------------
// MFMA flash cross-attention (R4 structure: block = 64 q x head x batch,
// wave owns 16 q, 64-key chunks; no occupancy clamp -> no spills).
// Reads fused KV ([row][256]: K cols 0-127, V cols 128-255). Q pre-scaled.
// No-max softmax (scores O(1)), deferred l, permuted-P packed b64 writes.
// ---------------------------------------------------------------------------
__global__ __launch_bounds__(256)
void attn_mfma_kernel(const unsigned short* __restrict__ Qh,
                      const unsigned short* __restrict__ KVh,
                      unsigned short* __restrict__ Obh)
{
    __shared__ unsigned short Ks[64 * 40];     // [key][dim 0..31 padded]
    __shared__ unsigned short Vt[16 * 72];     // [dim][key'] (permuted keys)
    __shared__ unsigned short Ps[4][16 * 72];  // per-wave [q][key']

    const int tid  = threadIdx.x;
    const int lane = tid & 63, wave = tid >> 6;
    const int quad = lane >> 4, l16 = lane & 15;
    const int q0 = blockIdx.x * 64, h = blockIdx.y, b = blockIdx.z;

    {   // zero K dim-pad (dims 16..31) once
        int key = tid >> 2, dg = tid & 3;
        ushort4 z; z.x = 0; z.y = 0; z.z = 0; z.w = 0;
        *(ushort4*)&Ks[key * 40 + 16 + dg * 4] = z;
    }

    short8 qa = {};
    if (quad < 2) {
        qa = *(const short8*)&Qh[((size_t)b * 1024 + q0 + wave * 16 + l16) * 128 + h * 16 + quad * 8];
    }

    f32x4 o = {0.f, 0.f, 0.f, 0.f};
    float l0[4] = {0.f, 0.f, 0.f, 0.f};
    unsigned short* Pw = &Ps[wave][0];

    for (int k0 = 0; k0 < 1024; k0 += 64) {
        __syncthreads();
        {   // stage K (natural rows) and V (permuted cols) from fused KV
            int kk = tid >> 2, dg = tid & 3;
            size_t g = ((size_t)b * 1024 + k0 + kk) * 256 + h * 16 + dg * 4;
            ushort4 kv = *(const ushort4*)&KVh[g];
            *(ushort4*)&Ks[kk * 40 + dg * 4] = kv;
            ushort4 vv = *(const ushort4*)&KVh[g + 128];
            int col2 = (kk & 15) * 4 + (kk >> 4);
            Vt[(dg * 4 + 0) * 72 + col2] = vv.x;
            Vt[(dg * 4 + 1) * 72 + col2] = vv.y;
            Vt[(dg * 4 + 2) * 72 + col2] = vv.z;
            Vt[(dg * 4 + 3) * 72 + col2] = vv.w;
        }
        __syncthreads();

        f32x4 s[4];
        f32x4 zc = {0.f, 0.f, 0.f, 0.f};
        #pragma unroll
        for (int g = 0; g < 4; ++g) {
            short8 kb = *(const short8*)&Ks[(g * 16 + l16) * 40 + quad * 8];
            s[g] = __builtin_amdgcn_mfma_f32_16x16x32_bf16(qa, kb, zc, 0, 0, 0);
        }

        #pragma unroll
        for (int r = 0; r < 4; ++r) {
            float p0 = __expf(s[0][r]);
            float p1 = __expf(s[1][r]);
            float p2 = __expf(s[2][r]);
            float p3 = __expf(s[3][r]);
            l0[r] += (p0 + p1) + (p2 + p3);
            unsigned q01 = __builtin_amdgcn_perm(__builtin_bit_cast(unsigned, p1),
                                                 __builtin_bit_cast(unsigned, p0), 0x07060302u);
            unsigned q23 = __builtin_amdgcn_perm(__builtin_bit_cast(unsigned, p3),
                                                 __builtin_bit_cast(unsigned, p2), 0x07060302u);
            uint2 pk; pk.x = q01; pk.y = q23;
            *(uint2*)&Pw[(quad * 4 + r) * 72 + l16 * 4] = pk;   // cols l16*4+g
        }
        asm volatile("s_waitcnt lgkmcnt(0)" ::: "memory");

        #pragma unroll
        for (int t = 0; t < 2; ++t) {
            short8 pa = *(const short8*)&Pw[l16 * 72 + t * 32 + quad * 8];
            short8 vb = *(const short8*)&Vt[l16 * 72 + t * 32 + quad * 8];
            o = __builtin_amdgcn_mfma_f32_16x16x32_bf16(pa, vb, o, 0, 0, 0);
        }
    }

    #pragma unroll
    for (int r = 0; r < 4; ++r) {
        float lr = l0[r];
        #pragma unroll
        for (int off = 1; off < 16; off <<= 1) lr += __shfl_xor(lr, off, 64);
        float linv = 1.0f / lr;
        int qrow = q0 + wave * 16 + quad * 4 + r;
        Obh[((size_t)b * 1024 + qrow) * 128 + h * 16 + l16] = f2bf(o[r] * linv);
    }
}

// ---------------------------------------------------------------------------
// y = LN(y + t) * g + b; writes f32 master and bf16 shadow
// ---------------------------------------------------------------------------
__global__ __launch_bounds__(256)
void resid_ln_kernel(float* __restrict__ y, const float* __restrict__ t,
                     const float* __restrict__ g, const float* __restrict__ bb,
                     unsigned short* __restrict__ yh)
{
    int r = blockIdx.x * 4 + (threadIdx.x >> 6);
    int lane = threadIdx.x & 63;
    size_t base = (size_t)r * 128;
    float v0 = y[base + lane]      + t[base + lane];
    float v1 = y[base + 64 + lane] + t[base + 64 + lane];
    float s = v0 + v1;
    #pragma unroll
    for (int off = 32; off; off >>= 1) s += __shfl_xor(s, off, 64);
    float mu = s * (1.0f / 128.0f);
    float d0 = v0 - mu, d1 = v1 - mu;
    float q = d0 * d0 + d1 * d1;
    #pragma unroll
    for (int off = 32; off; off >>= 1) q += __shfl_xor(q, off, 64);
    float inv = rsqrtf(q * (1.0f / 128.0f) + 1e-5f);
    float o0 = d0 * inv * g[lane]      + bb[lane];
    float o1 = d1 * inv * g[lane + 64] + bb[lane + 64];
    y[base + lane]      = o0;
    y[base + 64 + lane] = o1;
    yh[base + lane]      = f2bf(o0);
    yh[base + 64 + lane] = f2bf(o1);
}

// ---------------------------------------------------------------------------
extern "C" void kernel_launch(void* const* d_in, const int* in_sizes, int n_in,
                              void* d_out, int out_size, void* d_ws, size_t ws_size,
                              hipStream_t stream)
{
    const float* enc  = (const float*)d_in[0];
    const float* xraw = (const float*)d_in[2];
    const int*   ei   = (const int*)d_in[3];
    const float* Wg1  = (const float*)d_in[4];
    const float* bg1  = (const float*)d_in[5];
    const float* Wg2  = (const float*)d_in[6];
    const float* bg2  = (const float*)d_in[7];
    const float* Wq   = (const float*)d_in[8];
    const float* Wk   = (const float*)d_in[9];
    const float* Wv   = (const float*)d_in[10];
    const float* Wo   = (const float*)d_in[11];
    const float* Wff1 = (const float*)d_in[12];
    const float* bff1 = (const float*)d_in[13];
    const float* Wff2 = (const float*)d_in[14];
    const float* bff2 = (const float*)d_in[15];
    const float* ln1g = (const float*)d_in[16];
    const float* ln1b = (const float*)d_in[17];
    const float* ln2g = (const float*)d_in[18];
    const float* ln2b = (const float*)d_in[19];

    const int E  = in_sizes[3] / 2;            // 524288
    const int N  = in_sizes[2] / 128;          // 32768
    const int BM = in_sizes[0] / 128;          // 32768
    const int B  = BM / 1024;                  // 32
    const int L  = in_sizes[8] / (128 * 128);  // 2

    const int* srcE = ei;
    const int* dstE = ei + E;

    const size_t ND = (size_t)N * 128;         // 4194304
    float* ws   = (float*)d_ws;
    float* dinv = ws;                          // N f32
    float* bufY = ws + 32768;                  // ND f32 (residual master)
    float* bufA = bufY + ND;                   // ND f32 (pre-LN temp)
    unsigned short* ush   = (unsigned short*)(bufA + ND);
    unsigned short* bufYh = ush;               // ND bf16 (residual shadow)
    unsigned short* xrawh = bufYh + ND;        // ND
    unsigned short* hsh   = xrawh + ND;        // ND (GCN gemm out)
    unsigned short* bufBh = hsh + ND;          // ND (GCN features / KV src)
    unsigned short* region = bufBh + ND;       // 4*ND bf16
    unsigned short* Qh  = region;              // ND
    unsigned short* KVh = region + ND;         // 2*ND ([row][256]: K | V)
    unsigned short* Th  = region + 3 * ND;     // ND (attn out)
    unsigned short* Hh  = region;              // FFN hidden (4*ND), overlaps
    unsigned short* wt  = region + 4 * ND;     // 425984 bf16
    int* cnt     = (int*)(wt + 425984);        // N
    int* csr_off = cnt + N;                    // N+1
    int* cursor  = csr_off + N + 1;            // N
    int* csr_src = cursor + N;                 // E

    // --- CSR + dinv ---
    hipMemsetAsync(cnt, 0, (size_t)N * sizeof(int), stream);
    count_kernel<<<(E + 255) / 256, 256, 0, stream>>>(dstE, cnt, E);
    dinv_kernel<<<(N + 255) / 256, 256, 0, stream>>>(cnt, dinv, N);
    scan_kernel<<<1, 1024, 0, stream>>>(cnt, csr_off, cursor, N);
    place_kernel<<<(E + 255) / 256, 256, 0, stream>>>(srcE, dstE, cursor, csr_src, E);

    // --- converts + weight transpose ---
    conv_kernel<<<(int)(ND / 1024), 256, 0, stream>>>(xraw, xrawh);
    copyconv_kernel<<<(int)(ND / 1024), 256, 0, stream>>>(enc, bufY, bufYh);
    wtrans_kernel<<<dim3(256, 14), 256, 0, stream>>>(Wg1, Wg2, Wq, Wk, Wv, Wo, Wff1, Wff2, wt);

    // --- GCN layer 1 ---
    gemm_mfma_kernel<<<dim3(N / 128, 1), 256, 0, stream>>>(xrawh, wt, hsh, 128, 128, nullptr, dinv, 0, 1);
    gather_kernel<<<N / 4, 256, 0, stream>>>(hsh, csr_off, csr_src, dinv, bg1, bufBh, N);
    // --- GCN layer 2 ---
    gemm_mfma_kernel<<<dim3(N / 128, 1), 256, 0, stream>>>(bufBh, wt + 16384, hsh, 128, 128, nullptr, dinv, 0, 1);
    gather_kernel<<<N / 4, 256, 0, stream>>>(hsh, csr_off, csr_src, dinv, bg2, bufBh, N);
    // bufBh = GCN features (KV source)

    for (int l = 0; l < L; ++l) {
        const unsigned short* wtq  = wt + 32768  + (size_t)l * 16384;
        const unsigned short* wtkv = wt + 65536  + (size_t)l * 32768;
        const unsigned short* wto  = wt + 131072 + (size_t)l * 16384;
        const unsigned short* wtf1 = wt + 163840 + (size_t)l * 65536;
        const unsigned short* wtf2 = wt + 294912 + (size_t)l * 65536;

        gemm_mfma_kernel<<<dim3(BM / 128, 1), 256, 0, stream>>>(bufYh, wtq, Qh, 128, 128, nullptr, nullptr, 0, 1);
        gemm_mfma_kernel<<<dim3(N / 128, 2), 256, 0, stream>>>(bufBh, wtkv, KVh, 128, 256, nullptr, nullptr, 0, 1);

        attn_mfma_kernel<<<dim3(16, 8, B), 256, 0, stream>>>(Qh, KVh, Th);

        gemm_mfma_kernel<<<dim3(BM / 128, 1), 256, 0, stream>>>(Th, wto, bufA, 128, 128, nullptr, nullptr, 0, 0);
        resid_ln_kernel<<<BM / 4, 256, 0, stream>>>(bufY, bufA, ln1g + l * 128, ln1b + l * 128, bufYh);

        gemm_mfma_kernel<<<dim3(BM / 128, 4), 256, 0, stream>>>(bufYh, wtf1, Hh, 128, 512, bff1 + l * 512, nullptr, 1, 1);
        gemm_mfma_kernel<<<dim3(BM / 128, 1), 256, 0, stream>>>(Hh, wtf2, bufA, 512, 128, bff2 + l * 128, nullptr, 0, 0);
        resid_ln_kernel<<<BM / 4, 256, 0, stream>>>(bufY, bufA, ln2g + l * 128, ln2b + l * 128, bufYh);
    }

    hipMemcpyAsync(d_out, bufY, (size_t)out_size * sizeof(float), hipMemcpyDeviceToDevice, stream);
}

// Round 7
// 629.825 us; speedup vs baseline: 1.7654x; 1.0051x over previous
//
#include <hip/hip_runtime.h>
#include <math.h>

// GCN(2 layers, N=32768, E=524288, d=128) -> 2-layer cross-attention
// transformer (B=32, M=1024, d=128, H=8, dh=16, dff=512).
// R7: (1) GEMM tile 64x128 with BK=128 (single-stage K, one barrier pair,
//     grid 512 = 2 blocks/CU) on mfma_32x32x16;
//     (2) attention: K staged at permuted slots ((kk&3)*16 + kk>>2) so
//     MFMA column l16 = key l16*4+g -> P packed writes land in NATURAL key
//     order; V pre-transposed globally by the KV-GEMM epilogue (mode=2) and
//     staged with b128 loads/writes. No scalar LDS writes, no col2 math.

typedef __attribute__((ext_vector_type(8)))  short short8;   // 8 bf16 = 4 VGPRs
typedef __attribute__((ext_vector_type(4)))  float f32x4;
typedef __attribute__((ext_vector_type(16))) float f32x16;

__device__ __forceinline__ unsigned short f2bf(float x) {   // RNE fp32->bf16
    unsigned u = __builtin_bit_cast(unsigned, x);
    u = (u + 0x7FFFu + ((u >> 16) & 1u)) >> 16;
    return (unsigned short)u;
}
__device__ __forceinline__ float bflo(unsigned u) { return __builtin_bit_cast(float, u << 16); }
__device__ __forceinline__ float bfhi(unsigned u) { return __builtin_bit_cast(float, u & 0xffff0000u); }

// ---------------------------------------------------------------------------
// CSR build
// ---------------------------------------------------------------------------
__global__ void count_kernel(const int* __restrict__ dst, int* __restrict__ cnt, int E) {
    int e = blockIdx.x * 256 + threadIdx.x;
    if (e < E) atomicAdd(&cnt[dst[e]], 1);
}

__global__ void dinv_kernel(const int* __restrict__ cnt, float* __restrict__ dinv, int N) {
    int i = blockIdx.x * 256 + threadIdx.x;
    if (i < N) dinv[i] = rsqrtf((float)cnt[i] + 1.0f);   // +1 self-loop
}

__global__ __launch_bounds__(1024)
void scan_kernel(const int* __restrict__ cnt, int* __restrict__ off,
                 int* __restrict__ cursor, int N)
{
    __shared__ int part[1024];
    const int t = threadIdx.x;
    int local[32];
    int s = 0;
    #pragma unroll
    for (int i = 0; i < 32; ++i) { local[i] = cnt[t * 32 + i]; s += local[i]; }
    part[t] = s;
    __syncthreads();
    int run = s;
    for (int o = 1; o < 1024; o <<= 1) {
        int v = (t >= o) ? part[t - o] : 0;
        __syncthreads();
        part[t] += v;
        __syncthreads();
    }
    int pre = part[t] - run;
    #pragma unroll
    for (int i = 0; i < 32; ++i) {
        off[t * 32 + i] = pre;
        cursor[t * 32 + i] = pre;
        pre += local[i];
    }
    if (t == 1023) off[N] = pre;
}

__global__ void place_kernel(const int* __restrict__ src, const int* __restrict__ dst,
                             int* __restrict__ cursor, int* __restrict__ csr_src, int E)
{
    int e = blockIdx.x * 256 + threadIdx.x;
    if (e < E) {
        int p = atomicAdd(&cursor[dst[e]], 1);
        csr_src[p] = src[e];
    }
}

// ---------------------------------------------------------------------------
// Conversions
// ---------------------------------------------------------------------------
__global__ void conv_kernel(const float* __restrict__ src, unsigned short* __restrict__ dst) {
    int i = blockIdx.x * 256 + threadIdx.x;
    float4 v = ((const float4*)src)[i];
    ushort4 h; h.x = f2bf(v.x); h.y = f2bf(v.y); h.z = f2bf(v.z); h.w = f2bf(v.w);
    ((ushort4*)dst)[i] = h;
}

__global__ void copyconv_kernel(const float* __restrict__ src, float* __restrict__ dstf,
                                unsigned short* __restrict__ dsth) {
    int i = blockIdx.x * 256 + threadIdx.x;
    float4 v = ((const float4*)src)[i];
    ((float4*)dstf)[i] = v;
    ushort4 h; h.x = f2bf(v.x); h.y = f2bf(v.y); h.z = f2bf(v.z); h.w = f2bf(v.w);
    ((ushort4*)dsth)[i] = h;
}

// ---------------------------------------------------------------------------
// Weight transpose+convert. K/V of each layer land as one 256-row matrix.
// Wq is scaled by 0.25 (= 1/sqrt(dh)).
// ---------------------------------------------------------------------------
__global__ __launch_bounds__(256)
void wtrans_kernel(const float* Wg1, const float* Wg2, const float* Wq, const float* Wk,
                   const float* Wv, const float* Wo, const float* Wff1, const float* Wff2,
                   unsigned short* __restrict__ out)
{
    const int slot = blockIdx.y;
    const float* src; int ks; int Ns; size_t doff; float scale = 1.0f;
    if      (slot == 0)  { src = Wg1;                        ks = 7; Ns = 128; doff = 0; }
    else if (slot == 1)  { src = Wg2;                        ks = 7; Ns = 128; doff = 16384; }
    else if (slot <= 3)  { src = Wq  + (slot - 2)  * 16384;  ks = 7; Ns = 128; doff = 32768  + (size_t)(slot - 2)  * 16384; scale = 0.25f; }
    else if (slot <= 5)  { src = Wk  + (slot - 4)  * 16384;  ks = 7; Ns = 128; doff = 65536  + (size_t)(slot - 4)  * 32768; }
    else if (slot <= 7)  { src = Wv  + (slot - 6)  * 16384;  ks = 7; Ns = 128; doff = 65536  + (size_t)(slot - 6)  * 32768 + 16384; }
    else if (slot <= 9)  { src = Wo  + (slot - 8)  * 16384;  ks = 7; Ns = 128; doff = 131072 + (size_t)(slot - 8)  * 16384; }
    else if (slot <= 11) { src = Wff1 + (slot - 10) * 65536; ks = 7; Ns = 512; doff = 163840 + (size_t)(slot - 10) * 65536; }
    else                 { src = Wff2 + (slot - 12) * 65536; ks = 9; Ns = 128; doff = 294912 + (size_t)(slot - 12) * 65536; }
    const int total = Ns << ks;
    int id = blockIdx.x * 256 + threadIdx.x;
    if (id >= total) return;
    int n = id >> ks;
    int k = id & ((1 << ks) - 1);
    out[doff + id] = f2bf(src[(size_t)k * Ns + n] * scale);
}

// ---------------------------------------------------------------------------
// MFMA GEMM on 32x32x16: C[M x ncols] = op(A @ W). Tile 64 rows x 128 cols,
// BK=128 (whole K staged per iteration -> 1 barrier pair per 128 K).
// 4 waves: wrow=(w&1)*32, wcol=(w>>1)*64; wave = 2x 32x32 tiles.
// mode: 0 = f32 out, 1 = bf16 out, 2 = KV (cols<128 -> C as [row][128] bf16;
// cols>=128 -> C2 = V transposed [b,h,d,key] bf16).
// C/D: col=lane&31, row=(reg&3)+8*(reg>>2)+4*(lane>>5)  [verified mapping].
// ---------------------------------------------------------------------------
__global__ __launch_bounds__(256)
void gemm_mfma_kernel(const unsigned short* __restrict__ A,
                      const unsigned short* __restrict__ Wt,
                      void* __restrict__ C, void* __restrict__ C2, int K, int ncols,
                      const float* __restrict__ bias, const float* __restrict__ rowscale,
                      int relu, int mode)
{
    __shared__ unsigned short As[64 * 136];    // [row][k0..127], stride 136
    __shared__ unsigned short Ws[128 * 136];   // [col][k0..127]

    const int tid  = threadIdx.x;
    const int lane = tid & 63, wave = tid >> 6;
    const int m31 = lane & 31, hi = lane >> 5;
    const int row0 = blockIdx.x * 64;
    const int c0   = blockIdx.y * 128;
    const int wrow = (wave & 1) * 32;
    const int wcol = (wave >> 1) * 64;

    const int ar = tid >> 2, ao = (tid & 3) * 32;   // A: row, k-base (4 chunks)
    const int wr = tid >> 1, wo = (tid & 1) * 64;   // W: row, k-base (8 chunks)

    f32x16 acc0 = {}, acc1 = {};

    for (int kt = 0; kt < K; kt += 128) {
        if (kt) __syncthreads();
        #pragma unroll
        for (int c = 0; c < 4; ++c)
            *(short8*)&As[ar * 136 + ao + c * 8] =
                *(const short8*)&A[(size_t)(row0 + ar) * K + kt + ao + c * 8];
        #pragma unroll
        for (int c = 0; c < 8; ++c)
            *(short8*)&Ws[wr * 136 + wo + c * 8] =
                *(const short8*)&Wt[(size_t)(c0 + wr) * K + kt + wo + c * 8];
        __syncthreads();
        #pragma unroll
        for (int kk = 0; kk < 8; ++kk) {
            short8 af = *(const short8*)&As[(wrow + m31) * 136 + kk * 16 + hi * 8];
            short8 b0 = *(const short8*)&Ws[(wcol + m31) * 136 + kk * 16 + hi * 8];
            short8 b1 = *(const short8*)&Ws[(wcol + 32 + m31) * 136 + kk * 16 + hi * 8];
            acc0 = __builtin_amdgcn_mfma_f32_32x32x16_bf16(af, b0, acc0, 0, 0, 0);
            acc1 = __builtin_amdgcn_mfma_f32_32x32x16_bf16(af, b1, acc1, 0, 0, 0);
        }
    }

    #pragma unroll
    for (int r = 0; r < 16; ++r) {
        const int row = row0 + wrow + (r & 3) + 8 * (r >> 2) + 4 * hi;
        const float rs = rowscale ? rowscale[row] : 1.0f;
        #pragma unroll
        for (int ct = 0; ct < 2; ++ct) {
            const int col = c0 + wcol + ct * 32 + m31;
            float v = (ct ? acc1[r] : acc0[r]) * rs;
            if (bias) v += bias[col];
            if (relu) v = fmaxf(v, 0.0f);
            if (mode == 0) {
                ((float*)C)[(size_t)row * ncols + col] = v;
            } else if (mode == 1) {
                ((unsigned short*)C)[(size_t)row * ncols + col] = f2bf(v);
            } else {    // KV: K natural (ncols 128), V transposed [b,h,d,key]
                if (col < 128) {
                    ((unsigned short*)C)[(size_t)row * 128 + col] = f2bf(v);
                } else {
                    int ch = col - 128, hh = ch >> 4, dd = ch & 15;
                    ((unsigned short*)C2)[(((size_t)(row >> 10) * 8 + hh) * 16 + dd) * 1024
                                          + (row & 1023)] = f2bf(v);
                }
            }
        }
    }
}

// ---------------------------------------------------------------------------
// GCN gather (bf16 in/out): one wave per node, 2 channels per lane.
// ---------------------------------------------------------------------------
__global__ __launch_bounds__(256)
void gather_kernel(const unsigned short* __restrict__ hs, const int* __restrict__ csr_off,
                   const int* __restrict__ csr_src, const float* __restrict__ dinv,
                   const float* __restrict__ bias, unsigned short* __restrict__ out, int N)
{
    const int node = blockIdx.x * 4 + (threadIdx.x >> 6);
    const int lane = threadIdx.x & 63;
    const int s0 = csr_off[node], s1 = csr_off[node + 1];
    const unsigned* hsu = (const unsigned*)hs;

    unsigned u = hsu[(size_t)node * 64 + lane];
    float a0 = bflo(u), a1 = bfhi(u);

    for (int base = s0; base < s1; base += 64) {
        int cnt = s1 - base; if (cnt > 64) cnt = 64;
        int idx = (base + lane < s1) ? csr_src[base + lane] : 0;
        int j = 0;
        for (; j + 4 <= cnt; j += 4) {
            size_t sA = (size_t)__shfl(idx, j,     64) * 64;
            size_t sB = (size_t)__shfl(idx, j + 1, 64) * 64;
            size_t sC = (size_t)__shfl(idx, j + 2, 64) * 64;
            size_t sD = (size_t)__shfl(idx, j + 3, 64) * 64;
            unsigned uA = hsu[sA + lane], uB = hsu[sB + lane];
            unsigned uC = hsu[sC + lane], uD = hsu[sD + lane];
            a0 += (bflo(uA) + bflo(uB)) + (bflo(uC) + bflo(uD));
            a1 += (bfhi(uA) + bfhi(uB)) + (bfhi(uC) + bfhi(uD));
        }
        for (; j < cnt; ++j) {
            size_t sb = (size_t)__shfl(idx, j, 64) * 64;
            unsigned ub = hsu[sb + lane];
            a0 += bflo(ub); a1 += bfhi(ub);
        }
    }
    float di = dinv[node];
    float v0 = fmaxf(a0 * di + bias[lane * 2],     0.0f);
    float v1 = fmaxf(a1 * di + bias[lane * 2 + 1], 0.0f);
    ((unsigned*)out)[(size_t)node * 64 + lane] =
        ((unsigned)f2bf(v1) << 16) | (unsigned)f2bf(v0);
}

// ---------------------------------------------------------------------------
// MFMA flash cross-attention. Block = (64q, head, batch), wave owns 16 q.
// K rows staged at slot (kk&3)*16 + (kk>>2): MFMA g's column l16 = key
// l16*4+g -> P packed-b64 writes are in natural key order. V read from the
// globally pre-transposed Vtg [b,h,d,key]: b128 load + b128 LDS write.
// No-max softmax (scores O(1), Q pre-scaled), deferred l.
// ---------------------------------------------------------------------------
__global__ __launch_bounds__(256)
void attn_mfma_kernel(const unsigned short* __restrict__ Qh,
                      const unsigned short* __restrict__ Kg,
                      const unsigned short* __restrict__ Vtg,
                      unsigned short* __restrict__ Obh)
{
    __shared__ unsigned short Ks[64 * 40];     // [slot][dim 0..31 padded]
    __shared__ unsigned short Vt[16 * 72];     // [dim][key 0..63 natural]
    __shared__ unsigned short Ps[4][16 * 72];  // per-wave [q][key natural]

    const int tid  = threadIdx.x;
    const int lane = tid & 63, wave = tid >> 6;
    const int quad = lane >> 4, l16 = lane & 15;
    const int q0 = blockIdx.x * 64, h = blockIdx.y, b = blockIdx.z;

    if (tid < 128) {   // zero K dim-pad (dims 16..31) once
        short8 z = {};
        *(short8*)&Ks[(tid >> 1) * 40 + 16 + (tid & 1) * 8] = z;
    }

    short8 qa = {};
    if (quad < 2) {
        qa = *(const short8*)&Qh[((size_t)b * 1024 + q0 + wave * 16 + l16) * 128 + h * 16 + quad * 8];
    }

    f32x4 o = {0.f, 0.f, 0.f, 0.f};
    float l0[4] = {0.f, 0.f, 0.f, 0.f};
    unsigned short* Pw = &Ps[wave][0];

    for (int k0 = 0; k0 < 1024; k0 += 64) {
        __syncthreads();
        if (tid < 128) {   // stage K at permuted slots
            int key = tid >> 1, half = tid & 1;
            int slot = (key & 3) * 16 + (key >> 2);
            *(short8*)&Ks[slot * 40 + half * 8] =
                *(const short8*)&Kg[((size_t)b * 1024 + k0 + key) * 128 + h * 16 + half * 8];
        } else {           // stage V rows (natural key order)
            int t2 = tid - 128, dim = t2 >> 3, kc = t2 & 7;
            *(short8*)&Vt[dim * 72 + kc * 8] =
                *(const short8*)&Vtg[(((size_t)b * 8 + h) * 16 + dim) * 1024 + k0 + kc * 8];
        }
        __syncthreads();

        // S: MFMA g, col l16 = key l16*4+g, rows quad*4+r
        f32x4 s[4];
        f32x4 zc = {0.f, 0.f, 0.f, 0.f};
        #pragma unroll
        for (int g = 0; g < 4; ++g) {
            short8 kb = *(const short8*)&Ks[(g * 16 + l16) * 40 + quad * 8];
            s[g] = __builtin_amdgcn_mfma_f32_16x16x32_bf16(qa, kb, zc, 0, 0, 0);
        }

        #pragma unroll
        for (int r = 0; r < 4; ++r) {
            float p0 = __expf(s[0][r]);
            float p1 = __expf(s[1][r]);
            float p2 = __expf(s[2][r]);
            float p3 = __expf(s[3][r]);
            l0[r] += (p0 + p1) + (p2 + p3);
            unsigned q01 = __builtin_amdgcn_perm(__builtin_bit_cast(unsigned, p1),
                                                 __builtin_bit_cast(unsigned, p0), 0x07060302u);
            unsigned q23 = __builtin_amdgcn_perm(__builtin_bit_cast(unsigned, p3),
                                                 __builtin_bit_cast(unsigned, p2), 0x07060302u);
            uint2 pk; pk.x = q01; pk.y = q23;
            *(uint2*)&Pw[(quad * 4 + r) * 72 + l16 * 4] = pk;   // keys l16*4+g (natural)
        }
        asm volatile("s_waitcnt lgkmcnt(0)" ::: "memory");

        #pragma unroll
        for (int t = 0; t < 2; ++t) {
            short8 pa = *(const short8*)&Pw[l16 * 72 + t * 32 + quad * 8];
            short8 vb = *(const short8*)&Vt[l16 * 72 + t * 32 + quad * 8];
            o = __builtin_amdgcn_mfma_f32_16x16x32_bf16(pa, vb, o, 0, 0, 0);
        }
    }

    #pragma unroll
    for (int r = 0; r < 4; ++r) {
        float lr = l0[r];
        #pragma unroll
        for (int off = 1; off < 16; off <<= 1) lr += __shfl_xor(lr, off, 64);
        float linv = 1.0f / lr;
        int qrow = q0 + wave * 16 + quad * 4 + r;
        Obh[((size_t)b * 1024 + qrow) * 128 + h * 16 + l16] = f2bf(o[r] * linv);
    }
}

// ---------------------------------------------------------------------------
// y = LN(y + t) * g + b; writes f32 master and bf16 shadow
// ---------------------------------------------------------------------------
__global__ __launch_bounds__(256)
void resid_ln_kernel(float* __restrict__ y, const float* __restrict__ t,
                     const float* __restrict__ g, const float* __restrict__ bb,
                     unsigned short* __restrict__ yh)
{
    int r = blockIdx.x * 4 + (threadIdx.x >> 6);
    int lane = threadIdx.x & 63;
    size_t base = (size_t)r * 128;
    float v0 = y[base + lane]      + t[base + lane];
    float v1 = y[base + 64 + lane] + t[base + 64 + lane];
    float s = v0 + v1;
    #pragma unroll
    for (int off = 32; off; off >>= 1) s += __shfl_xor(s, off, 64);
    float mu = s * (1.0f / 128.0f);
    float d0 = v0 - mu, d1 = v1 - mu;
    float q = d0 * d0 + d1 * d1;
    #pragma unroll
    for (int off = 32; off; off >>= 1) q += __shfl_xor(q, off, 64);
    float inv = rsqrtf(q * (1.0f / 128.0f) + 1e-5f);
    float o0 = d0 * inv * g[lane]      + bb[lane];
    float o1 = d1 * inv * g[lane + 64] + bb[lane + 64];
    y[base + lane]      = o0;
    y[base + 64 + lane] = o1;
    yh[base + lane]      = f2bf(o0);
    yh[base + 64 + lane] = f2bf(o1);
}

// ---------------------------------------------------------------------------
extern "C" void kernel_launch(void* const* d_in, const int* in_sizes, int n_in,
                              void* d_out, int out_size, void* d_ws, size_t ws_size,
                              hipStream_t stream)
{
    const float* enc  = (const float*)d_in[0];
    const float* xraw = (const float*)d_in[2];
    const int*   ei   = (const int*)d_in[3];
    const float* Wg1  = (const float*)d_in[4];
    const float* bg1  = (const float*)d_in[5];
    const float* Wg2  = (const float*)d_in[6];
    const float* bg2  = (const float*)d_in[7];
    const float* Wq   = (const float*)d_in[8];
    const float* Wk   = (const float*)d_in[9];
    const float* Wv   = (const float*)d_in[10];
    const float* Wo   = (const float*)d_in[11];
    const float* Wff1 = (const float*)d_in[12];
    const float* bff1 = (const float*)d_in[13];
    const float* Wff2 = (const float*)d_in[14];
    const float* bff2 = (const float*)d_in[15];
    const float* ln1g = (const float*)d_in[16];
    const float* ln1b = (const float*)d_in[17];
    const float* ln2g = (const float*)d_in[18];
    const float* ln2b = (const float*)d_in[19];

    const int E  = in_sizes[3] / 2;            // 524288
    const int N  = in_sizes[2] / 128;          // 32768
    const int BM = in_sizes[0] / 128;          // 32768
    const int B  = BM / 1024;                  // 32
    const int L  = in_sizes[8] / (128 * 128);  // 2

    const int* srcE = ei;
    const int* dstE = ei + E;

    const size_t ND = (size_t)N * 128;         // 4194304
    float* ws   = (float*)d_ws;
    float* dinv = ws;                          // N f32
    float* bufY = ws + 32768;                  // ND f32 (residual master)
    float* bufA = bufY + ND;                   // ND f32 (pre-LN temp)
    unsigned short* ush   = (unsigned short*)(bufA + ND);
    unsigned short* bufYh = ush;               // ND bf16 (residual shadow)
    unsigned short* xrawh = bufYh + ND;        // ND
    unsigned short* hsh   = xrawh + ND;        // ND (GCN gemm out)
    unsigned short* bufBh = hsh + ND;          // ND (GCN features / KV src)
    unsigned short* region = bufBh + ND;       // 4*ND bf16
    unsigned short* Qh  = region;              // ND
    unsigned short* Kg  = region + ND;         // ND  [b*1024+key][128]
    unsigned short* Vtg = region + 2 * ND;     // ND  [b,h,d][1024 keys]
    unsigned short* Th  = region + 3 * ND;     // ND (attn out)
    unsigned short* Hh  = region;              // FFN hidden (4*ND), overlaps
    unsigned short* wt  = region + 4 * ND;     // 425984 bf16
    int* cnt     = (int*)(wt + 425984);        // N
    int* csr_off = cnt + N;                    // N+1
    int* cursor  = csr_off + N + 1;            // N
    int* csr_src = cursor + N;                 // E

    // --- CSR + dinv ---
    hipMemsetAsync(cnt, 0, (size_t)N * sizeof(int), stream);
    count_kernel<<<(E + 255) / 256, 256, 0, stream>>>(dstE, cnt, E);
    dinv_kernel<<<(N + 255) / 256, 256, 0, stream>>>(cnt, dinv, N);
    scan_kernel<<<1, 1024, 0, stream>>>(cnt, csr_off, cursor, N);
    place_kernel<<<(E + 255) / 256, 256, 0, stream>>>(srcE, dstE, cursor, csr_src, E);

    // --- converts + weight transpose ---
    conv_kernel<<<(int)(ND / 1024), 256, 0, stream>>>(xraw, xrawh);
    copyconv_kernel<<<(int)(ND / 1024), 256, 0, stream>>>(enc, bufY, bufYh);
    wtrans_kernel<<<dim3(256, 14), 256, 0, stream>>>(Wg1, Wg2, Wq, Wk, Wv, Wo, Wff1, Wff2, wt);

    // --- GCN layer 1 ---
    gemm_mfma_kernel<<<dim3(N / 64, 1), 256, 0, stream>>>(xrawh, wt, hsh, nullptr, 128, 128, nullptr, dinv, 0, 1);
    gather_kernel<<<N / 4, 256, 0, stream>>>(hsh, csr_off, csr_src, dinv, bg1, bufBh, N);
    // --- GCN layer 2 ---
    gemm_mfma_kernel<<<dim3(N / 64, 1), 256, 0, stream>>>(bufBh, wt + 16384, hsh, nullptr, 128, 128, nullptr, dinv, 0, 1);
    gather_kernel<<<N / 4, 256, 0, stream>>>(hsh, csr_off, csr_src, dinv, bg2, bufBh, N);
    // bufBh = GCN features (KV source)

    for (int l = 0; l < L; ++l) {
        const unsigned short* wtq  = wt + 32768  + (size_t)l * 16384;
        const unsigned short* wtkv = wt + 65536  + (size_t)l * 32768;
        const unsigned short* wto  = wt + 131072 + (size_t)l * 16384;
        const unsigned short* wtf1 = wt + 163840 + (size_t)l * 65536;
        const unsigned short* wtf2 = wt + 294912 + (size_t)l * 65536;

        gemm_mfma_kernel<<<dim3(BM / 64, 1), 256, 0, stream>>>(bufYh, wtq, Qh, nullptr, 128, 128, nullptr, nullptr, 0, 1);
        gemm_mfma_kernel<<<dim3(N / 64, 2), 256, 0, stream>>>(bufBh, wtkv, Kg, Vtg, 128, 256, nullptr, nullptr, 0, 2);

        attn_mfma_kernel<<<dim3(16, 8, B), 256, 0, stream>>>(Qh, Kg, Vtg, Th);

        gemm_mfma_kernel<<<dim3(BM / 64, 1), 256, 0, stream>>>(Th, wto, bufA, nullptr, 128, 128, nullptr, nullptr, 0, 0);
        resid_ln_kernel<<<BM / 4, 256, 0, stream>>>(bufY, bufA, ln1g + l * 128, ln1b + l * 128, bufYh);

        gemm_mfma_kernel<<<dim3(BM / 64, 4), 256, 0, stream>>>(bufYh, wtf1, Hh, nullptr, 128, 512, bff1 + l * 512, nullptr, 1, 1);
        gemm_mfma_kernel<<<dim3(BM / 64, 1), 256, 0, stream>>>(Hh, wtf2, bufA, nullptr, 512, 128, bff2 + l * 128, nullptr, 0, 0);
        resid_ln_kernel<<<BM / 4, 256, 0, stream>>>(bufY, bufA, ln2g + l * 128, ln2b + l * 128, bufYh);
    }

    hipMemcpyAsync(d_out, bufY, (size_t)out_size * sizeof(float), hipMemcpyDeviceToDevice, stream);
}

// Round 8
// 613.504 us; speedup vs baseline: 1.8123x; 1.0266x over previous
//
#include <hip/hip_runtime.h>
#include <math.h>

// GCN(2 layers, N=32768, E=524288, d=128) -> 2-layer cross-attention
// transformer (B=32, M=1024, d=128, H=8, dh=16, dff=512).
// R8: (1) attn: exp2-folded scale (raw v_exp_f32), 128-key chunks (half the
//     barriers), P packed as one b128 write; (2) LN fused into ncols=128
//     GEMM epilogue (mode 3) -> 4 resid_ln dispatches + bufA round-trips
//     gone; (3) final fused GEMM writes d_out directly (no D2D copy).

typedef __attribute__((ext_vector_type(8)))  short short8;   // 8 bf16 = 4 VGPRs
typedef __attribute__((ext_vector_type(4)))  float f32x4;
typedef __attribute__((ext_vector_type(16))) float f32x16;

__device__ __forceinline__ unsigned short f2bf(float x) {   // RNE fp32->bf16
    unsigned u = __builtin_bit_cast(unsigned, x);
    u = (u + 0x7FFFu + ((u >> 16) & 1u)) >> 16;
    return (unsigned short)u;
}
__device__ __forceinline__ float bflo(unsigned u) { return __builtin_bit_cast(float, u << 16); }
__device__ __forceinline__ float bfhi(unsigned u) { return __builtin_bit_cast(float, u & 0xffff0000u); }
__device__ __forceinline__ float fast_exp2(float x) {       // D = 2^S0
    float r; asm("v_exp_f32 %0, %1" : "=v"(r) : "v"(x)); return r;
}

// ---------------------------------------------------------------------------
// CSR build
// ---------------------------------------------------------------------------
__global__ void count_kernel(const int* __restrict__ dst, int* __restrict__ cnt, int E) {
    int e = blockIdx.x * 256 + threadIdx.x;
    if (e < E) atomicAdd(&cnt[dst[e]], 1);
}

__global__ void dinv_kernel(const int* __restrict__ cnt, float* __restrict__ dinv, int N) {
    int i = blockIdx.x * 256 + threadIdx.x;
    if (i < N) dinv[i] = rsqrtf((float)cnt[i] + 1.0f);   // +1 self-loop
}

__global__ __launch_bounds__(1024)
void scan_kernel(const int* __restrict__ cnt, int* __restrict__ off,
                 int* __restrict__ cursor, int N)
{
    __shared__ int part[1024];
    const int t = threadIdx.x;
    int local[32];
    int s = 0;
    #pragma unroll
    for (int i = 0; i < 32; ++i) { local[i] = cnt[t * 32 + i]; s += local[i]; }
    part[t] = s;
    __syncthreads();
    int run = s;
    for (int o = 1; o < 1024; o <<= 1) {
        int v = (t >= o) ? part[t - o] : 0;
        __syncthreads();
        part[t] += v;
        __syncthreads();
    }
    int pre = part[t] - run;
    #pragma unroll
    for (int i = 0; i < 32; ++i) {
        off[t * 32 + i] = pre;
        cursor[t * 32 + i] = pre;
        pre += local[i];
    }
    if (t == 1023) off[N] = pre;
}

__global__ void place_kernel(const int* __restrict__ src, const int* __restrict__ dst,
                             int* __restrict__ cursor, int* __restrict__ csr_src, int E)
{
    int e = blockIdx.x * 256 + threadIdx.x;
    if (e < E) {
        int p = atomicAdd(&cursor[dst[e]], 1);
        csr_src[p] = src[e];
    }
}

// ---------------------------------------------------------------------------
// Conversions
// ---------------------------------------------------------------------------
__global__ void conv_kernel(const float* __restrict__ src, unsigned short* __restrict__ dst) {
    int i = blockIdx.x * 256 + threadIdx.x;
    float4 v = ((const float4*)src)[i];
    ushort4 h; h.x = f2bf(v.x); h.y = f2bf(v.y); h.z = f2bf(v.z); h.w = f2bf(v.w);
    ((ushort4*)dst)[i] = h;
}

__global__ void copyconv_kernel(const float* __restrict__ src, float* __restrict__ dstf,
                                unsigned short* __restrict__ dsth) {
    int i = blockIdx.x * 256 + threadIdx.x;
    float4 v = ((const float4*)src)[i];
    ((float4*)dstf)[i] = v;
    ushort4 h; h.x = f2bf(v.x); h.y = f2bf(v.y); h.z = f2bf(v.z); h.w = f2bf(v.w);
    ((ushort4*)dsth)[i] = h;
}

// ---------------------------------------------------------------------------
// Weight transpose+convert. K/V of each layer land as one 256-row matrix.
// Wq scale = 0.25 * log2(e): scores come out pre-multiplied for exp2.
// ---------------------------------------------------------------------------
__global__ __launch_bounds__(256)
void wtrans_kernel(const float* Wg1, const float* Wg2, const float* Wq, const float* Wk,
                   const float* Wv, const float* Wo, const float* Wff1, const float* Wff2,
                   unsigned short* __restrict__ out)
{
    const int slot = blockIdx.y;
    const float* src; int ks; int Ns; size_t doff; float scale = 1.0f;
    if      (slot == 0)  { src = Wg1;                        ks = 7; Ns = 128; doff = 0; }
    else if (slot == 1)  { src = Wg2;                        ks = 7; Ns = 128; doff = 16384; }
    else if (slot <= 3)  { src = Wq  + (slot - 2)  * 16384;  ks = 7; Ns = 128; doff = 32768  + (size_t)(slot - 2)  * 16384; scale = 0.36067376022f; }
    else if (slot <= 5)  { src = Wk  + (slot - 4)  * 16384;  ks = 7; Ns = 128; doff = 65536  + (size_t)(slot - 4)  * 32768; }
    else if (slot <= 7)  { src = Wv  + (slot - 6)  * 16384;  ks = 7; Ns = 128; doff = 65536  + (size_t)(slot - 6)  * 32768 + 16384; }
    else if (slot <= 9)  { src = Wo  + (slot - 8)  * 16384;  ks = 7; Ns = 128; doff = 131072 + (size_t)(slot - 8)  * 16384; }
    else if (slot <= 11) { src = Wff1 + (slot - 10) * 65536; ks = 7; Ns = 512; doff = 163840 + (size_t)(slot - 10) * 65536; }
    else                 { src = Wff2 + (slot - 12) * 65536; ks = 9; Ns = 128; doff = 294912 + (size_t)(slot - 12) * 65536; }
    const int total = Ns << ks;
    int id = blockIdx.x * 256 + threadIdx.x;
    if (id >= total) return;
    int n = id >> ks;
    int k = id & ((1 << ks) - 1);
    out[doff + id] = f2bf(src[(size_t)k * Ns + n] * scale);
}

// ---------------------------------------------------------------------------
// MFMA GEMM on 32x32x16: tile 64x128, BK=128. 4 waves: wrow=(w&1)*32,
// wcol=(w>>1)*64, each wave 2x 32x32 tiles.
// mode 0: f32 out. mode 1: bf16 out. mode 2: KV split (K natural, V
// transposed [b,h,d,key]). mode 3: fused residual+LN (ncols must be 128):
// t=acc(+bias); y'=LN(resid_in+t)*lng+lnb -> resid_out f32 + yh bf16.
// C/D: col=lane&31, row=(reg&3)+8*(reg>>2)+4*(lane>>5)  [verified mapping].
// ---------------------------------------------------------------------------
__global__ __launch_bounds__(256)
void gemm_mfma_kernel(const unsigned short* __restrict__ A,
                      const unsigned short* __restrict__ Wt,
                      void* __restrict__ C, void* __restrict__ C2, int K, int ncols,
                      const float* __restrict__ bias, const float* __restrict__ rowscale,
                      int relu, int mode,
                      const float* __restrict__ resid_in, float* __restrict__ resid_out,
                      unsigned short* __restrict__ yh,
                      const float* __restrict__ lng, const float* __restrict__ lnb)
{
    __shared__ __align__(16) unsigned short sm[26112];   // As 64x136 | Ws 128x136
    unsigned short* As = sm;           // [row][k]
    unsigned short* Ws = sm + 8704;    // [col][k]

    const int tid  = threadIdx.x;
    const int lane = tid & 63, wave = tid >> 6;
    const int m31 = lane & 31, hi = lane >> 5;
    const int row0 = blockIdx.x * 64;
    const int c0   = blockIdx.y * 128;
    const int wrow = (wave & 1) * 32;
    const int wcol = (wave >> 1) * 64;

    const int ar = tid >> 2, ao = (tid & 3) * 32;   // A: row, k-base
    const int wr = tid >> 1, wo = (tid & 1) * 64;   // W: row, k-base

    f32x16 acc0 = {}, acc1 = {};

    for (int kt = 0; kt < K; kt += 128) {
        if (kt) __syncthreads();
        #pragma unroll
        for (int c = 0; c < 4; ++c)
            *(short8*)&As[ar * 136 + ao + c * 8] =
                *(const short8*)&A[(size_t)(row0 + ar) * K + kt + ao + c * 8];
        #pragma unroll
        for (int c = 0; c < 8; ++c)
            *(short8*)&Ws[wr * 136 + wo + c * 8] =
                *(const short8*)&Wt[(size_t)(c0 + wr) * K + kt + wo + c * 8];
        __syncthreads();
        #pragma unroll
        for (int kk = 0; kk < 8; ++kk) {
            short8 af = *(const short8*)&As[(wrow + m31) * 136 + kk * 16 + hi * 8];
            short8 b0 = *(const short8*)&Ws[(wcol + m31) * 136 + kk * 16 + hi * 8];
            short8 b1 = *(const short8*)&Ws[(wcol + 32 + m31) * 136 + kk * 16 + hi * 8];
            acc0 = __builtin_amdgcn_mfma_f32_32x32x16_bf16(af, b0, acc0, 0, 0, 0);
            acc1 = __builtin_amdgcn_mfma_f32_32x32x16_bf16(af, b1, acc1, 0, 0, 0);
        }
    }

    if (mode == 3) {
        // --- fused residual + LayerNorm (ncols == 128) ---
        __syncthreads();                       // LDS now dead; reuse as stash
        float* Ts = (float*)sm;                // [64][130]
        #pragma unroll
        for (int r = 0; r < 16; ++r) {
            const int rl = wrow + (r & 3) + 8 * (r >> 2) + 4 * hi;
            #pragma unroll
            for (int ct = 0; ct < 2; ++ct) {
                const int col = wcol + ct * 32 + m31;
                float v = ct ? acc1[r] : acc0[r];
                if (bias) v += bias[col];
                Ts[rl * 130 + col] = v;
            }
        }
        __syncthreads();
        const int r  = tid >> 2;               // 0..63
        const int cq = tid & 3;                // 32-col group
        const int row = row0 + r;
        float v[32], s1 = 0.f, s2 = 0.f;
        const float* yr = resid_in + (size_t)row * 128 + cq * 32;
        #pragma unroll
        for (int i = 0; i < 8; ++i) {
            float4 yv = *(const float4*)&yr[i * 4];
            float ys[4] = {yv.x, yv.y, yv.z, yv.w};
            #pragma unroll
            for (int j = 0; j < 4; ++j) {
                float t = Ts[r * 130 + cq * 32 + i * 4 + j] + ys[j];
                v[i * 4 + j] = t; s1 += t; s2 += t * t;
            }
        }
        s1 += __shfl_xor(s1, 1, 64); s1 += __shfl_xor(s1, 2, 64);
        s2 += __shfl_xor(s2, 1, 64); s2 += __shfl_xor(s2, 2, 64);
        const float mu  = s1 * (1.0f / 128.0f);
        const float inv = rsqrtf(s2 * (1.0f / 128.0f) - mu * mu + 1e-5f);
        float* outr = resid_out + (size_t)row * 128 + cq * 32;
        unsigned short* yhr = yh + (size_t)row * 128 + cq * 32;
        #pragma unroll
        for (int i = 0; i < 8; ++i) {
            float o0 = (v[i*4+0] - mu) * inv * lng[cq*32 + i*4 + 0] + lnb[cq*32 + i*4 + 0];
            float o1 = (v[i*4+1] - mu) * inv * lng[cq*32 + i*4 + 1] + lnb[cq*32 + i*4 + 1];
            float o2 = (v[i*4+2] - mu) * inv * lng[cq*32 + i*4 + 2] + lnb[cq*32 + i*4 + 2];
            float o3 = (v[i*4+3] - mu) * inv * lng[cq*32 + i*4 + 3] + lnb[cq*32 + i*4 + 3];
            float4 ov; ov.x = o0; ov.y = o1; ov.z = o2; ov.w = o3;
            *(float4*)&outr[i * 4] = ov;
            ushort4 hv; hv.x = f2bf(o0); hv.y = f2bf(o1); hv.z = f2bf(o2); hv.w = f2bf(o3);
            *(ushort4*)&yhr[i * 4] = hv;
        }
        return;
    }

    #pragma unroll
    for (int r = 0; r < 16; ++r) {
        const int row = row0 + wrow + (r & 3) + 8 * (r >> 2) + 4 * hi;
        const float rs = rowscale ? rowscale[row] : 1.0f;
        #pragma unroll
        for (int ct = 0; ct < 2; ++ct) {
            const int col = c0 + wcol + ct * 32 + m31;
            float v = (ct ? acc1[r] : acc0[r]) * rs;
            if (bias) v += bias[col];
            if (relu) v = fmaxf(v, 0.0f);
            if (mode == 0) {
                ((float*)C)[(size_t)row * ncols + col] = v;
            } else if (mode == 1) {
                ((unsigned short*)C)[(size_t)row * ncols + col] = f2bf(v);
            } else {    // KV: K natural (128 cols), V transposed [b,h,d,key]
                if (col < 128) {
                    ((unsigned short*)C)[(size_t)row * 128 + col] = f2bf(v);
                } else {
                    int ch = col - 128, hh = ch >> 4, dd = ch & 15;
                    ((unsigned short*)C2)[(((size_t)(row >> 10) * 8 + hh) * 16 + dd) * 1024
                                          + (row & 1023)] = f2bf(v);
                }
            }
        }
    }
}

// ---------------------------------------------------------------------------
// GCN gather (bf16 in/out): one wave per node, 2 channels per lane.
// ---------------------------------------------------------------------------
__global__ __launch_bounds__(256)
void gather_kernel(const unsigned short* __restrict__ hs, const int* __restrict__ csr_off,
                   const int* __restrict__ csr_src, const float* __restrict__ dinv,
                   const float* __restrict__ bias, unsigned short* __restrict__ out, int N)
{
    const int node = blockIdx.x * 4 + (threadIdx.x >> 6);
    const int lane = threadIdx.x & 63;
    const int s0 = csr_off[node], s1 = csr_off[node + 1];
    const unsigned* hsu = (const unsigned*)hs;

    unsigned u = hsu[(size_t)node * 64 + lane];
    float a0 = bflo(u), a1 = bfhi(u);

    for (int base = s0; base < s1; base += 64) {
        int cnt = s1 - base; if (cnt > 64) cnt = 64;
        int idx = (base + lane < s1) ? csr_src[base + lane] : 0;
        int j = 0;
        for (; j + 4 <= cnt; j += 4) {
            size_t sA = (size_t)__shfl(idx, j,     64) * 64;
            size_t sB = (size_t)__shfl(idx, j + 1, 64) * 64;
            size_t sC = (size_t)__shfl(idx, j + 2, 64) * 64;
            size_t sD = (size_t)__shfl(idx, j + 3, 64) * 64;
            unsigned uA = hsu[sA + lane], uB = hsu[sB + lane];
            unsigned uC = hsu[sC + lane], uD = hsu[sD + lane];
            a0 += (bflo(uA) + bflo(uB)) + (bflo(uC) + bflo(uD));
            a1 += (bfhi(uA) + bfhi(uB)) + (bfhi(uC) + bfhi(uD));
        }
        for (; j < cnt; ++j) {
            size_t sb = (size_t)__shfl(idx, j, 64) * 64;
            unsigned ub = hsu[sb + lane];
            a0 += bflo(ub); a1 += bfhi(ub);
        }
    }
    float di = dinv[node];
    float v0 = fmaxf(a0 * di + bias[lane * 2],     0.0f);
    float v1 = fmaxf(a1 * di + bias[lane * 2 + 1], 0.0f);
    ((unsigned*)out)[(size_t)node * 64 + lane] =
        ((unsigned)f2bf(v1) << 16) | (unsigned)f2bf(v0);
}

// ---------------------------------------------------------------------------
// MFMA flash cross-attention. Block = (64q, head, batch), wave owns 16 q.
// 128-key chunks (8 iterations). K rows staged at slot (key&7)*16+(key>>3):
// MFMA g's column l16 = key l16*8+g -> P packed-b128 writes in natural key
// order. V from globally pre-transposed Vtg [b,h,d,key]. Scores arrive
// pre-scaled by 0.25*log2(e) -> raw v_exp_f32 (2^x), no mul. Deferred l.
// ---------------------------------------------------------------------------
__global__ __launch_bounds__(256)
void attn_mfma_kernel(const unsigned short* __restrict__ Qh,
                      const unsigned short* __restrict__ Kg,
                      const unsigned short* __restrict__ Vtg,
                      unsigned short* __restrict__ Obh)
{
    __shared__ unsigned short Ks[128 * 40];    // [slot][dim 0..31 padded]
    __shared__ unsigned short Vt[16 * 136];    // [dim][key 0..127]
    __shared__ unsigned short Ps[4][16 * 136]; // per-wave [q][key]

    const int tid  = threadIdx.x;
    const int lane = tid & 63, wave = tid >> 6;
    const int quad = lane >> 4, l16 = lane & 15;
    const int q0 = blockIdx.x * 64, h = blockIdx.y, b = blockIdx.z;

    {   // zero K dim-pad (dims 16..31) for all 128 slots, once
        short8 z = {};
        *(short8*)&Ks[(tid >> 1) * 40 + 16 + (tid & 1) * 8] = z;
    }

    short8 qa = {};
    if (quad < 2) {
        qa = *(const short8*)&Qh[((size_t)b * 1024 + q0 + wave * 16 + l16) * 128 + h * 16 + quad * 8];
    }

    f32x4 o = {0.f, 0.f, 0.f, 0.f};
    float l0[4] = {0.f, 0.f, 0.f, 0.f};
    unsigned short* Pw = &Ps[wave][0];

    for (int k0 = 0; k0 < 1024; k0 += 128) {
        __syncthreads();
        {   // stage 128 K rows (permuted slots) + 16 V rows (natural)
            int key = tid >> 1, half = (tid & 1) * 8;
            int slot = (key & 7) * 16 + (key >> 3);
            *(short8*)&Ks[slot * 40 + half] =
                *(const short8*)&Kg[((size_t)b * 1024 + k0 + key) * 128 + h * 16 + half];
            int dim = tid >> 4, kc = (tid & 15) * 8;
            *(short8*)&Vt[dim * 136 + kc] =
                *(const short8*)&Vtg[(((size_t)b * 8 + h) * 16 + dim) * 1024 + k0 + kc];
        }
        __syncthreads();

        // S: MFMA g covers keys l16*8+g (g=0..7), rows quad*4+r
        f32x4 s[8];
        f32x4 zc = {0.f, 0.f, 0.f, 0.f};
        #pragma unroll
        for (int g = 0; g < 8; ++g) {
            short8 kb = *(const short8*)&Ks[(g * 16 + l16) * 40 + quad * 8];
            s[g] = __builtin_amdgcn_mfma_f32_16x16x32_bf16(qa, kb, zc, 0, 0, 0);
        }

        #pragma unroll
        for (int r = 0; r < 4; ++r) {
            float p0 = fast_exp2(s[0][r]);
            float p1 = fast_exp2(s[1][r]);
            float p2 = fast_exp2(s[2][r]);
            float p3 = fast_exp2(s[3][r]);
            float p4 = fast_exp2(s[4][r]);
            float p5 = fast_exp2(s[5][r]);
            float p6 = fast_exp2(s[6][r]);
            float p7 = fast_exp2(s[7][r]);
            l0[r] += ((p0 + p1) + (p2 + p3)) + ((p4 + p5) + (p6 + p7));
            uint4 pk;
            pk.x = __builtin_amdgcn_perm(__builtin_bit_cast(unsigned, p1),
                                         __builtin_bit_cast(unsigned, p0), 0x07060302u);
            pk.y = __builtin_amdgcn_perm(__builtin_bit_cast(unsigned, p3),
                                         __builtin_bit_cast(unsigned, p2), 0x07060302u);
            pk.z = __builtin_amdgcn_perm(__builtin_bit_cast(unsigned, p5),
                                         __builtin_bit_cast(unsigned, p4), 0x07060302u);
            pk.w = __builtin_amdgcn_perm(__builtin_bit_cast(unsigned, p7),
                                         __builtin_bit_cast(unsigned, p6), 0x07060302u);
            *(uint4*)&Pw[(quad * 4 + r) * 136 + l16 * 8] = pk;   // keys l16*8+g
        }
        asm volatile("s_waitcnt lgkmcnt(0)" ::: "memory");

        #pragma unroll
        for (int t = 0; t < 4; ++t) {
            short8 pa = *(const short8*)&Pw[l16 * 136 + t * 32 + quad * 8];
            short8 vb = *(const short8*)&Vt[l16 * 136 + t * 32 + quad * 8];
            o = __builtin_amdgcn_mfma_f32_16x16x32_bf16(pa, vb, o, 0, 0, 0);
        }
    }

    #pragma unroll
    for (int r = 0; r < 4; ++r) {
        float lr = l0[r];
        #pragma unroll
        for (int off = 1; off < 16; off <<= 1) lr += __shfl_xor(lr, off, 64);
        float linv = 1.0f / lr;
        int qrow = q0 + wave * 16 + quad * 4 + r;
        Obh[((size_t)b * 1024 + qrow) * 128 + h * 16 + l16] = f2bf(o[r] * linv);
    }
}

// ---------------------------------------------------------------------------
extern "C" void kernel_launch(void* const* d_in, const int* in_sizes, int n_in,
                              void* d_out, int out_size, void* d_ws, size_t ws_size,
                              hipStream_t stream)
{
    const float* enc  = (const float*)d_in[0];
    const float* xraw = (const float*)d_in[2];
    const int*   ei   = (const int*)d_in[3];
    const float* Wg1  = (const float*)d_in[4];
    const float* bg1  = (const float*)d_in[5];
    const float* Wg2  = (const float*)d_in[6];
    const float* bg2  = (const float*)d_in[7];
    const float* Wq   = (const float*)d_in[8];
    const float* Wk   = (const float*)d_in[9];
    const float* Wv   = (const float*)d_in[10];
    const float* Wo   = (const float*)d_in[11];
    const float* Wff1 = (const float*)d_in[12];
    const float* bff1 = (const float*)d_in[13];
    const float* Wff2 = (const float*)d_in[14];
    const float* bff2 = (const float*)d_in[15];
    const float* ln1g = (const float*)d_in[16];
    const float* ln1b = (const float*)d_in[17];
    const float* ln2g = (const float*)d_in[18];
    const float* ln2b = (const float*)d_in[19];

    const int E  = in_sizes[3] / 2;            // 524288
    const int N  = in_sizes[2] / 128;          // 32768
    const int BM = in_sizes[0] / 128;          // 32768
    const int B  = BM / 1024;                  // 32
    const int L  = in_sizes[8] / (128 * 128);  // 2

    const int* srcE = ei;
    const int* dstE = ei + E;

    const size_t ND = (size_t)N * 128;         // 4194304
    float* ws   = (float*)d_ws;
    float* dinv = ws;                          // N f32
    float* bufY = ws + 32768;                  // ND f32 (residual master)
    float* bufA = bufY + ND;                   // ND f32 (unused now, kept)
    unsigned short* ush   = (unsigned short*)(bufA + ND);
    unsigned short* bufYh = ush;               // ND bf16 (residual shadow)
    unsigned short* xrawh = bufYh + ND;        // ND
    unsigned short* hsh   = xrawh + ND;        // ND (GCN gemm out)
    unsigned short* bufBh = hsh + ND;          // ND (GCN features / KV src)
    unsigned short* region = bufBh + ND;       // 4*ND bf16
    unsigned short* Qh  = region;              // ND
    unsigned short* Kg  = region + ND;         // ND  [b*1024+key][128]
    unsigned short* Vtg = region + 2 * ND;     // ND  [b,h,d][1024 keys]
    unsigned short* Th  = region + 3 * ND;     // ND (attn out)
    unsigned short* Hh  = region;              // FFN hidden (4*ND), overlaps
    unsigned short* wt  = region + 4 * ND;     // 425984 bf16
    int* cnt     = (int*)(wt + 425984);        // N
    int* csr_off = cnt + N;                    // N+1
    int* cursor  = csr_off + N + 1;            // N
    int* csr_src = cursor + N;                 // E

    // --- CSR + dinv ---
    hipMemsetAsync(cnt, 0, (size_t)N * sizeof(int), stream);
    count_kernel<<<(E + 255) / 256, 256, 0, stream>>>(dstE, cnt, E);
    dinv_kernel<<<(N + 255) / 256, 256, 0, stream>>>(cnt, dinv, N);
    scan_kernel<<<1, 1024, 0, stream>>>(cnt, csr_off, cursor, N);
    place_kernel<<<(E + 255) / 256, 256, 0, stream>>>(srcE, dstE, cursor, csr_src, E);

    // --- converts + weight transpose ---
    conv_kernel<<<(int)(ND / 1024), 256, 0, stream>>>(xraw, xrawh);
    copyconv_kernel<<<(int)(ND / 1024), 256, 0, stream>>>(enc, bufY, bufYh);
    wtrans_kernel<<<dim3(256, 14), 256, 0, stream>>>(Wg1, Wg2, Wq, Wk, Wv, Wo, Wff1, Wff2, wt);

    // --- GCN layer 1 ---
    gemm_mfma_kernel<<<dim3(N / 64, 1), 256, 0, stream>>>(xrawh, wt, hsh, nullptr, 128, 128,
        nullptr, dinv, 0, 1, nullptr, nullptr, nullptr, nullptr, nullptr);
    gather_kernel<<<N / 4, 256, 0, stream>>>(hsh, csr_off, csr_src, dinv, bg1, bufBh, N);
    // --- GCN layer 2 ---
    gemm_mfma_kernel<<<dim3(N / 64, 1), 256, 0, stream>>>(bufBh, wt + 16384, hsh, nullptr, 128, 128,
        nullptr, dinv, 0, 1, nullptr, nullptr, nullptr, nullptr, nullptr);
    gather_kernel<<<N / 4, 256, 0, stream>>>(hsh, csr_off, csr_src, dinv, bg2, bufBh, N);
    // bufBh = GCN features (KV source)

    for (int l = 0; l < L; ++l) {
        const unsigned short* wtq  = wt + 32768  + (size_t)l * 16384;
        const unsigned short* wtkv = wt + 65536  + (size_t)l * 32768;
        const unsigned short* wto  = wt + 131072 + (size_t)l * 16384;
        const unsigned short* wtf1 = wt + 163840 + (size_t)l * 65536;
        const unsigned short* wtf2 = wt + 294912 + (size_t)l * 65536;

        gemm_mfma_kernel<<<dim3(BM / 64, 1), 256, 0, stream>>>(bufYh, wtq, Qh, nullptr, 128, 128,
            nullptr, nullptr, 0, 1, nullptr, nullptr, nullptr, nullptr, nullptr);
        gemm_mfma_kernel<<<dim3(N / 64, 2), 256, 0, stream>>>(bufBh, wtkv, Kg, Vtg, 128, 256,
            nullptr, nullptr, 0, 2, nullptr, nullptr, nullptr, nullptr, nullptr);

        attn_mfma_kernel<<<dim3(16, 8, B), 256, 0, stream>>>(Qh, Kg, Vtg, Th);

        // O-proj + residual + LN1 (fused)
        gemm_mfma_kernel<<<dim3(BM / 64, 1), 256, 0, stream>>>(Th, wto, nullptr, nullptr, 128, 128,
            nullptr, nullptr, 0, 3, bufY, bufY, bufYh, ln1g + l * 128, ln1b + l * 128);

        gemm_mfma_kernel<<<dim3(BM / 64, 4), 256, 0, stream>>>(bufYh, wtf1, Hh, nullptr, 128, 512,
            bff1 + l * 512, nullptr, 1, 1, nullptr, nullptr, nullptr, nullptr, nullptr);

        // FFN2 + residual + LN2 (fused); final layer writes d_out directly
        float* rout = (l == L - 1) ? (float*)d_out : bufY;
        gemm_mfma_kernel<<<dim3(BM / 64, 1), 256, 0, stream>>>(Hh, wtf2, nullptr, nullptr, 512, 128,
            bff2 + l * 128, nullptr, 0, 3, bufY, rout, bufYh, ln2g + l * 128, ln2b + l * 128);
    }
}

// Round 9
// 549.573 us; speedup vs baseline: 2.0231x; 1.1163x over previous
//
#include <hip/hip_runtime.h>
#include <math.h>

// GCN(2 layers, N=32768, E=524288, d=128) -> 2-layer cross-attention
// transformer (B=32, M=1024, d=128, H=8, dh=16, dff=512).
// R9: (1) GEMMs back to high-occupancy geometry: 64x64 tile BK=64 (18 KB LDS,
//     8 wg/CU); fused-LN GEMMs 64x128 BK=64 (33 KB, 4 wg/CU) — R4 evidence
//     says small GEMMs here are latency-bound, occupancy wins;
//     (2) single-block scan replaced by 3-kernel hierarchical scan (coalesced),
//     dinv folded in; (3) attention unchanged from R8 (73 us, known floor).

typedef __attribute__((ext_vector_type(8)))  short short8;   // 8 bf16 = 4 VGPRs
typedef __attribute__((ext_vector_type(4)))  float f32x4;
typedef __attribute__((ext_vector_type(16))) float f32x16;

__device__ __forceinline__ unsigned short f2bf(float x) {   // RNE fp32->bf16
    unsigned u = __builtin_bit_cast(unsigned, x);
    u = (u + 0x7FFFu + ((u >> 16) & 1u)) >> 16;
    return (unsigned short)u;
}
__device__ __forceinline__ float bflo(unsigned u) { return __builtin_bit_cast(float, u << 16); }
__device__ __forceinline__ float bfhi(unsigned u) { return __builtin_bit_cast(float, u & 0xffff0000u); }
__device__ __forceinline__ float fast_exp2(float x) {       // D = 2^S0
    float r; asm("v_exp_f32 %0, %1" : "=v"(r) : "v"(x)); return r;
}

// ---------------------------------------------------------------------------
// CSR build
// ---------------------------------------------------------------------------
__global__ void count_kernel(const int* __restrict__ dst, int* __restrict__ cnt, int E) {
    int e = blockIdx.x * 256 + threadIdx.x;
    if (e < E) atomicAdd(&cnt[dst[e]], 1);
}

// partial[b] = sum of cnt[b*256 .. b*256+255]
__global__ __launch_bounds__(256)
void scanA_kernel(const int* __restrict__ cnt, int* __restrict__ partial)
{
    __shared__ int wsum[4];
    int t = threadIdx.x;
    int v = cnt[blockIdx.x * 256 + t];
    #pragma unroll
    for (int off = 32; off; off >>= 1) v += __shfl_xor(v, off, 64);
    if ((t & 63) == 0) wsum[t >> 6] = v;
    __syncthreads();
    if (t == 0) partial[blockIdx.x] = wsum[0] + wsum[1] + wsum[2] + wsum[3];
}

// base = exclusive scan of partial[0..127]
__global__ __launch_bounds__(128)
void scanB_kernel(const int* __restrict__ partial, int* __restrict__ base)
{
    __shared__ int p[128];
    int t = threadIdx.x;
    int v = partial[t];
    p[t] = v;
    __syncthreads();
    for (int o = 1; o < 128; o <<= 1) {
        int q = (t >= o) ? p[t - o] : 0;
        __syncthreads();
        p[t] += q;
        __syncthreads();
    }
    base[t] = p[t] - v;   // exclusive
}

// off[i] = base[b] + exclusive-scan-within-block; cursor = off; dinv = rsqrt
__global__ __launch_bounds__(256)
void scanC_kernel(const int* __restrict__ cnt, const int* __restrict__ base,
                  int* __restrict__ off, int* __restrict__ cursor,
                  float* __restrict__ dinv, int N, int E)
{
    __shared__ int p[256];
    int t = threadIdx.x, b = blockIdx.x;
    int i = b * 256 + t;
    int c = cnt[i];
    p[t] = c;
    __syncthreads();
    for (int o = 1; o < 256; o <<= 1) {
        int q = (t >= o) ? p[t - o] : 0;
        __syncthreads();
        p[t] += q;
        __syncthreads();
    }
    int ex = base[b] + p[t] - c;
    off[i] = ex;
    cursor[i] = ex;
    dinv[i] = rsqrtf((float)c + 1.0f);
    if (b == 0 && t == 0) off[N] = E;
}

__global__ void place_kernel(const int* __restrict__ src, const int* __restrict__ dst,
                             int* __restrict__ cursor, int* __restrict__ csr_src, int E)
{
    int e = blockIdx.x * 256 + threadIdx.x;
    if (e < E) {
        int p = atomicAdd(&cursor[dst[e]], 1);
        csr_src[p] = src[e];
    }
}

// ---------------------------------------------------------------------------
// Conversions
// ---------------------------------------------------------------------------
__global__ void conv_kernel(const float* __restrict__ src, unsigned short* __restrict__ dst) {
    int i = blockIdx.x * 256 + threadIdx.x;
    float4 v = ((const float4*)src)[i];
    ushort4 h; h.x = f2bf(v.x); h.y = f2bf(v.y); h.z = f2bf(v.z); h.w = f2bf(v.w);
    ((ushort4*)dst)[i] = h;
}

__global__ void copyconv_kernel(const float* __restrict__ src, float* __restrict__ dstf,
                                unsigned short* __restrict__ dsth) {
    int i = blockIdx.x * 256 + threadIdx.x;
    float4 v = ((const float4*)src)[i];
    ((float4*)dstf)[i] = v;
    ushort4 h; h.x = f2bf(v.x); h.y = f2bf(v.y); h.z = f2bf(v.z); h.w = f2bf(v.w);
    ((ushort4*)dsth)[i] = h;
}

// ---------------------------------------------------------------------------
// Weight transpose+convert. K/V of each layer land as one 256-row matrix.
// Wq scale = 0.25 * log2(e): scores come out pre-multiplied for exp2.
// ---------------------------------------------------------------------------
__global__ __launch_bounds__(256)
void wtrans_kernel(const float* Wg1, const float* Wg2, const float* Wq, const float* Wk,
                   const float* Wv, const float* Wo, const float* Wff1, const float* Wff2,
                   unsigned short* __restrict__ out)
{
    const int slot = blockIdx.y;
    const float* src; int ks; int Ns; size_t doff; float scale = 1.0f;
    if      (slot == 0)  { src = Wg1;                        ks = 7; Ns = 128; doff = 0; }
    else if (slot == 1)  { src = Wg2;                        ks = 7; Ns = 128; doff = 16384; }
    else if (slot <= 3)  { src = Wq  + (slot - 2)  * 16384;  ks = 7; Ns = 128; doff = 32768  + (size_t)(slot - 2)  * 16384; scale = 0.36067376022f; }
    else if (slot <= 5)  { src = Wk  + (slot - 4)  * 16384;  ks = 7; Ns = 128; doff = 65536  + (size_t)(slot - 4)  * 32768; }
    else if (slot <= 7)  { src = Wv  + (slot - 6)  * 16384;  ks = 7; Ns = 128; doff = 65536  + (size_t)(slot - 6)  * 32768 + 16384; }
    else if (slot <= 9)  { src = Wo  + (slot - 8)  * 16384;  ks = 7; Ns = 128; doff = 131072 + (size_t)(slot - 8)  * 16384; }
    else if (slot <= 11) { src = Wff1 + (slot - 10) * 65536; ks = 7; Ns = 512; doff = 163840 + (size_t)(slot - 10) * 65536; }
    else                 { src = Wff2 + (slot - 12) * 65536; ks = 9; Ns = 128; doff = 294912 + (size_t)(slot - 12) * 65536; }
    const int total = Ns << ks;
    int id = blockIdx.x * 256 + threadIdx.x;
    if (id >= total) return;
    int n = id >> ks;
    int k = id & ((1 << ks) - 1);
    out[doff + id] = f2bf(src[(size_t)k * Ns + n] * scale);
}

// ---------------------------------------------------------------------------
// gemm64: 64x64 tile, BK=64, 18.4 KB LDS -> 8 wg/CU. Wave = one 32x32 MFMA
// tile (wrow=(w&1)*32, wcol=(w>>1)*32). mode 1: bf16 out (+bias/relu/rowscale)
// mode 2: KV split (col<128 -> K natural; col>=128 -> V transposed [b,h,d,key])
// C/D: col=lane&31, row=(reg&3)+8*(reg>>2)+4*(lane>>5)  [verified mapping].
// ---------------------------------------------------------------------------
__global__ __launch_bounds__(256)
void gemm64_kernel(const unsigned short* __restrict__ A,
                   const unsigned short* __restrict__ Wt,
                   void* __restrict__ C, void* __restrict__ C2, int K,
                   const float* __restrict__ bias, const float* __restrict__ rowscale,
                   int relu, int mode)
{
    __shared__ unsigned short As[64 * 72];
    __shared__ unsigned short Ws[64 * 72];

    const int tid  = threadIdx.x;
    const int lane = tid & 63, wave = tid >> 6;
    const int m31 = lane & 31, hi = lane >> 5;
    const int row0 = blockIdx.x * 64;
    const int c0   = blockIdx.y * 64;
    const int wrow = (wave & 1) * 32;
    const int wcol = (wave >> 1) * 32;
    const int sr = tid >> 2, sk = (tid & 3) * 16;

    f32x16 acc = {};

    for (int kt = 0; kt < K; kt += 64) {
        if (kt) __syncthreads();
        *(short8*)&As[sr * 72 + sk]     = *(const short8*)&A [(size_t)(row0 + sr) * K + kt + sk];
        *(short8*)&As[sr * 72 + sk + 8] = *(const short8*)&A [(size_t)(row0 + sr) * K + kt + sk + 8];
        *(short8*)&Ws[sr * 72 + sk]     = *(const short8*)&Wt[(size_t)(c0   + sr) * K + kt + sk];
        *(short8*)&Ws[sr * 72 + sk + 8] = *(const short8*)&Wt[(size_t)(c0   + sr) * K + kt + sk + 8];
        __syncthreads();
        #pragma unroll
        for (int ks = 0; ks < 4; ++ks) {
            short8 af = *(const short8*)&As[(wrow + m31) * 72 + ks * 16 + hi * 8];
            short8 bf = *(const short8*)&Ws[(wcol + m31) * 72 + ks * 16 + hi * 8];
            acc = __builtin_amdgcn_mfma_f32_32x32x16_bf16(af, bf, acc, 0, 0, 0);
        }
    }

    const int col = c0 + wcol + m31;
    #pragma unroll
    for (int r = 0; r < 16; ++r) {
        const int row = row0 + wrow + (r & 3) + 8 * (r >> 2) + 4 * hi;
        float v = acc[r];
        if (rowscale) v *= rowscale[row];
        if (bias) v += bias[col];
        if (relu) v = fmaxf(v, 0.0f);
        if (mode == 1) {
            ((unsigned short*)C)[(size_t)row * gridDim.y * 64 + col] = f2bf(v);
        } else {    // KV: K natural (128 cols), V transposed [b,h,d,key]
            if (col < 128) {
                ((unsigned short*)C)[(size_t)row * 128 + col] = f2bf(v);
            } else {
                int ch = col - 128, hh = ch >> 4, dd = ch & 15;
                ((unsigned short*)C2)[(((size_t)(row >> 10) * 8 + hh) * 16 + dd) * 1024
                                      + (row & 1023)] = f2bf(v);
            }
        }
    }
}

// ---------------------------------------------------------------------------
// gemm_ln: 64x128 tile, BK=64; epilogue = bias + residual + LayerNorm.
// Writes resid_out f32 + yh bf16. LDS reused as f32 stash [64][130].
// ---------------------------------------------------------------------------
__global__ __launch_bounds__(256)
void gemm_ln_kernel(const unsigned short* __restrict__ A,
                    const unsigned short* __restrict__ Wt, int K,
                    const float* __restrict__ bias,
                    const float* __restrict__ resid_in, float* __restrict__ resid_out,
                    unsigned short* __restrict__ yh,
                    const float* __restrict__ lng, const float* __restrict__ lnb)
{
    __shared__ __align__(16) unsigned char smraw[33280];  // As 9216 | Ws 18432; stash 33280
    unsigned short* As = (unsigned short*)smraw;           // [64][72]
    unsigned short* Ws = (unsigned short*)(smraw + 9216);  // [128][72]

    const int tid  = threadIdx.x;
    const int lane = tid & 63, wave = tid >> 6;
    const int m31 = lane & 31, hi = lane >> 5;
    const int row0 = blockIdx.x * 64;
    const int wrow = (wave & 1) * 32;
    const int wcol = (wave >> 1) * 64;
    const int sr = tid >> 2, sk = (tid & 3) * 16;   // A staging
    const int wr = tid >> 1, wo = (tid & 1) * 32;   // W staging

    f32x16 acc0 = {}, acc1 = {};

    for (int kt = 0; kt < K; kt += 64) {
        if (kt) __syncthreads();
        *(short8*)&As[sr * 72 + sk]      = *(const short8*)&A [(size_t)(row0 + sr) * K + kt + sk];
        *(short8*)&As[sr * 72 + sk + 8]  = *(const short8*)&A [(size_t)(row0 + sr) * K + kt + sk + 8];
        *(short8*)&Ws[wr * 72 + wo]      = *(const short8*)&Wt[(size_t)wr * K + kt + wo];
        *(short8*)&Ws[wr * 72 + wo + 8]  = *(const short8*)&Wt[(size_t)wr * K + kt + wo + 8];
        *(short8*)&Ws[wr * 72 + wo + 16] = *(const short8*)&Wt[(size_t)wr * K + kt + wo + 16];
        *(short8*)&Ws[wr * 72 + wo + 24] = *(const short8*)&Wt[(size_t)wr * K + kt + wo + 24];
        __syncthreads();
        #pragma unroll
        for (int ks = 0; ks < 4; ++ks) {
            short8 af = *(const short8*)&As[(wrow + m31) * 72 + ks * 16 + hi * 8];
            short8 b0 = *(const short8*)&Ws[(wcol + m31) * 72 + ks * 16 + hi * 8];
            short8 b1 = *(const short8*)&Ws[(wcol + 32 + m31) * 72 + ks * 16 + hi * 8];
            acc0 = __builtin_amdgcn_mfma_f32_32x32x16_bf16(af, b0, acc0, 0, 0, 0);
            acc1 = __builtin_amdgcn_mfma_f32_32x32x16_bf16(af, b1, acc1, 0, 0, 0);
        }
    }

    // --- stash t into LDS, then per-row residual + LN ---
    __syncthreads();
    float* Ts = (float*)smraw;    // [64][130]
    #pragma unroll
    for (int r = 0; r < 16; ++r) {
        const int rl = wrow + (r & 3) + 8 * (r >> 2) + 4 * hi;
        #pragma unroll
        for (int ct = 0; ct < 2; ++ct) {
            const int col = wcol + ct * 32 + m31;
            float v = ct ? acc1[r] : acc0[r];
            if (bias) v += bias[col];
            Ts[rl * 130 + col] = v;
        }
    }
    __syncthreads();
    const int r  = tid >> 2;
    const int cq = tid & 3;
    const int row = row0 + r;
    float v[32], s1 = 0.f, s2 = 0.f;
    const float* yr = resid_in + (size_t)row * 128 + cq * 32;
    #pragma unroll
    for (int i = 0; i < 8; ++i) {
        float4 yv = *(const float4*)&yr[i * 4];
        float ys[4] = {yv.x, yv.y, yv.z, yv.w};
        #pragma unroll
        for (int j = 0; j < 4; ++j) {
            float t = Ts[r * 130 + cq * 32 + i * 4 + j] + ys[j];
            v[i * 4 + j] = t; s1 += t; s2 += t * t;
        }
    }
    s1 += __shfl_xor(s1, 1, 64); s1 += __shfl_xor(s1, 2, 64);
    s2 += __shfl_xor(s2, 1, 64); s2 += __shfl_xor(s2, 2, 64);
    const float mu  = s1 * (1.0f / 128.0f);
    const float inv = rsqrtf(s2 * (1.0f / 128.0f) - mu * mu + 1e-5f);
    float* outr = resid_out + (size_t)row * 128 + cq * 32;
    unsigned short* yhr = yh + (size_t)row * 128 + cq * 32;
    #pragma unroll
    for (int i = 0; i < 8; ++i) {
        float o0 = (v[i*4+0] - mu) * inv * lng[cq*32 + i*4 + 0] + lnb[cq*32 + i*4 + 0];
        float o1 = (v[i*4+1] - mu) * inv * lng[cq*32 + i*4 + 1] + lnb[cq*32 + i*4 + 1];
        float o2 = (v[i*4+2] - mu) * inv * lng[cq*32 + i*4 + 2] + lnb[cq*32 + i*4 + 2];
        float o3 = (v[i*4+3] - mu) * inv * lng[cq*32 + i*4 + 3] + lnb[cq*32 + i*4 + 3];
        float4 ov; ov.x = o0; ov.y = o1; ov.z = o2; ov.w = o3;
        *(float4*)&outr[i * 4] = ov;
        ushort4 hv; hv.x = f2bf(o0); hv.y = f2bf(o1); hv.z = f2bf(o2); hv.w = f2bf(o3);
        *(ushort4*)&yhr[i * 4] = hv;
    }
}

// ---------------------------------------------------------------------------
// GCN gather (bf16 in/out): one wave per node, 2 channels per lane.
// ---------------------------------------------------------------------------
__global__ __launch_bounds__(256)
void gather_kernel(const unsigned short* __restrict__ hs, const int* __restrict__ csr_off,
                   const int* __restrict__ csr_src, const float* __restrict__ dinv,
                   const float* __restrict__ bias, unsigned short* __restrict__ out, int N)
{
    const int node = blockIdx.x * 4 + (threadIdx.x >> 6);
    const int lane = threadIdx.x & 63;
    const int s0 = csr_off[node], s1 = csr_off[node + 1];
    const unsigned* hsu = (const unsigned*)hs;

    unsigned u = hsu[(size_t)node * 64 + lane];
    float a0 = bflo(u), a1 = bfhi(u);

    for (int base = s0; base < s1; base += 64) {
        int cnt = s1 - base; if (cnt > 64) cnt = 64;
        int idx = (base + lane < s1) ? csr_src[base + lane] : 0;
        int j = 0;
        for (; j + 4 <= cnt; j += 4) {
            size_t sA = (size_t)__shfl(idx, j,     64) * 64;
            size_t sB = (size_t)__shfl(idx, j + 1, 64) * 64;
            size_t sC = (size_t)__shfl(idx, j + 2, 64) * 64;
            size_t sD = (size_t)__shfl(idx, j + 3, 64) * 64;
            unsigned uA = hsu[sA + lane], uB = hsu[sB + lane];
            unsigned uC = hsu[sC + lane], uD = hsu[sD + lane];
            a0 += (bflo(uA) + bflo(uB)) + (bflo(uC) + bflo(uD));
            a1 += (bfhi(uA) + bfhi(uB)) + (bfhi(uC) + bfhi(uD));
        }
        for (; j < cnt; ++j) {
            size_t sb = (size_t)__shfl(idx, j, 64) * 64;
            unsigned ub = hsu[sb + lane];
            a0 += bflo(ub); a1 += bfhi(ub);
        }
    }
    float di = dinv[node];
    float v0 = fmaxf(a0 * di + bias[lane * 2],     0.0f);
    float v1 = fmaxf(a1 * di + bias[lane * 2 + 1], 0.0f);
    ((unsigned*)out)[(size_t)node * 64 + lane] =
        ((unsigned)f2bf(v1) << 16) | (unsigned)f2bf(v0);
}

// ---------------------------------------------------------------------------
// MFMA flash cross-attention (unchanged from R8). Block = (64q, head, batch),
// wave owns 16 q, 128-key chunks. K rows at slot (key&7)*16+(key>>3) ->
// P packed-b128 writes in natural key order; V from pre-transposed Vtg.
// Scores pre-scaled by 0.25*log2(e) -> raw v_exp_f32. Deferred l.
// ---------------------------------------------------------------------------
__global__ __launch_bounds__(256)
void attn_mfma_kernel(const unsigned short* __restrict__ Qh,
                      const unsigned short* __restrict__ Kg,
                      const unsigned short* __restrict__ Vtg,
                      unsigned short* __restrict__ Obh)
{
    __shared__ unsigned short Ks[128 * 40];    // [slot][dim 0..31 padded]
    __shared__ unsigned short Vt[16 * 136];    // [dim][key 0..127]
    __shared__ unsigned short Ps[4][16 * 136]; // per-wave [q][key]

    const int tid  = threadIdx.x;
    const int lane = tid & 63, wave = tid >> 6;
    const int quad = lane >> 4, l16 = lane & 15;
    const int q0 = blockIdx.x * 64, h = blockIdx.y, b = blockIdx.z;

    {   // zero K dim-pad (dims 16..31) for all 128 slots, once
        short8 z = {};
        *(short8*)&Ks[(tid >> 1) * 40 + 16 + (tid & 1) * 8] = z;
    }

    short8 qa = {};
    if (quad < 2) {
        qa = *(const short8*)&Qh[((size_t)b * 1024 + q0 + wave * 16 + l16) * 128 + h * 16 + quad * 8];
    }

    f32x4 o = {0.f, 0.f, 0.f, 0.f};
    float l0[4] = {0.f, 0.f, 0.f, 0.f};
    unsigned short* Pw = &Ps[wave][0];

    for (int k0 = 0; k0 < 1024; k0 += 128) {
        __syncthreads();
        {   // stage 128 K rows (permuted slots) + 16 V rows (natural)
            int key = tid >> 1, half = (tid & 1) * 8;
            int slot = (key & 7) * 16 + (key >> 3);
            *(short8*)&Ks[slot * 40 + half] =
                *(const short8*)&Kg[((size_t)b * 1024 + k0 + key) * 128 + h * 16 + half];
            int dim = tid >> 4, kc = (tid & 15) * 8;
            *(short8*)&Vt[dim * 136 + kc] =
                *(const short8*)&Vtg[(((size_t)b * 8 + h) * 16 + dim) * 1024 + k0 + kc];
        }
        __syncthreads();

        f32x4 s[8];
        f32x4 zc = {0.f, 0.f, 0.f, 0.f};
        #pragma unroll
        for (int g = 0; g < 8; ++g) {
            short8 kb = *(const short8*)&Ks[(g * 16 + l16) * 40 + quad * 8];
            s[g] = __builtin_amdgcn_mfma_f32_16x16x32_bf16(qa, kb, zc, 0, 0, 0);
        }

        #pragma unroll
        for (int r = 0; r < 4; ++r) {
            float p0 = fast_exp2(s[0][r]);
            float p1 = fast_exp2(s[1][r]);
            float p2 = fast_exp2(s[2][r]);
            float p3 = fast_exp2(s[3][r]);
            float p4 = fast_exp2(s[4][r]);
            float p5 = fast_exp2(s[5][r]);
            float p6 = fast_exp2(s[6][r]);
            float p7 = fast_exp2(s[7][r]);
            l0[r] += ((p0 + p1) + (p2 + p3)) + ((p4 + p5) + (p6 + p7));
            uint4 pk;
            pk.x = __builtin_amdgcn_perm(__builtin_bit_cast(unsigned, p1),
                                         __builtin_bit_cast(unsigned, p0), 0x07060302u);
            pk.y = __builtin_amdgcn_perm(__builtin_bit_cast(unsigned, p3),
                                         __builtin_bit_cast(unsigned, p2), 0x07060302u);
            pk.z = __builtin_amdgcn_perm(__builtin_bit_cast(unsigned, p5),
                                         __builtin_bit_cast(unsigned, p4), 0x07060302u);
            pk.w = __builtin_amdgcn_perm(__builtin_bit_cast(unsigned, p7),
                                         __builtin_bit_cast(unsigned, p6), 0x07060302u);
            *(uint4*)&Pw[(quad * 4 + r) * 136 + l16 * 8] = pk;   // keys l16*8+g
        }
        asm volatile("s_waitcnt lgkmcnt(0)" ::: "memory");

        #pragma unroll
        for (int t = 0; t < 4; ++t) {
            short8 pa = *(const short8*)&Pw[l16 * 136 + t * 32 + quad * 8];
            short8 vb = *(const short8*)&Vt[l16 * 136 + t * 32 + quad * 8];
            o = __builtin_amdgcn_mfma_f32_16x16x32_bf16(pa, vb, o, 0, 0, 0);
        }
    }

    #pragma unroll
    for (int r = 0; r < 4; ++r) {
        float lr = l0[r];
        #pragma unroll
        for (int off = 1; off < 16; off <<= 1) lr += __shfl_xor(lr, off, 64);
        float linv = 1.0f / lr;
        int qrow = q0 + wave * 16 + quad * 4 + r;
        Obh[((size_t)b * 1024 + qrow) * 128 + h * 16 + l16] = f2bf(o[r] * linv);
    }
}

// ---------------------------------------------------------------------------
extern "C" void kernel_launch(void* const* d_in, const int* in_sizes, int n_in,
                              void* d_out, int out_size, void* d_ws, size_t ws_size,
                              hipStream_t stream)
{
    const float* enc  = (const float*)d_in[0];
    const float* xraw = (const float*)d_in[2];
    const int*   ei   = (const int*)d_in[3];
    const float* Wg1  = (const float*)d_in[4];
    const float* bg1  = (const float*)d_in[5];
    const float* Wg2  = (const float*)d_in[6];
    const float* bg2  = (const float*)d_in[7];
    const float* Wq   = (const float*)d_in[8];
    const float* Wk   = (const float*)d_in[9];
    const float* Wv   = (const float*)d_in[10];
    const float* Wo   = (const float*)d_in[11];
    const float* Wff1 = (const float*)d_in[12];
    const float* bff1 = (const float*)d_in[13];
    const float* Wff2 = (const float*)d_in[14];
    const float* bff2 = (const float*)d_in[15];
    const float* ln1g = (const float*)d_in[16];
    const float* ln1b = (const float*)d_in[17];
    const float* ln2g = (const float*)d_in[18];
    const float* ln2b = (const float*)d_in[19];

    const int E  = in_sizes[3] / 2;            // 524288
    const int N  = in_sizes[2] / 128;          // 32768
    const int BM = in_sizes[0] / 128;          // 32768
    const int B  = BM / 1024;                  // 32
    const int L  = in_sizes[8] / (128 * 128);  // 2

    const int* srcE = ei;
    const int* dstE = ei + E;

    const size_t ND = (size_t)N * 128;         // 4194304
    float* ws   = (float*)d_ws;
    float* dinv = ws;                          // N f32
    float* bufY = ws + 32768;                  // ND f32 (residual master)
    float* bufA = bufY + ND;                   // ND f32 (spare)
    unsigned short* ush   = (unsigned short*)(bufA + ND);
    unsigned short* bufYh = ush;               // ND bf16 (residual shadow)
    unsigned short* xrawh = bufYh + ND;        // ND
    unsigned short* hsh   = xrawh + ND;        // ND (GCN gemm out)
    unsigned short* bufBh = hsh + ND;          // ND (GCN features / KV src)
    unsigned short* region = bufBh + ND;       // 4*ND bf16
    unsigned short* Qh  = region;              // ND
    unsigned short* Kg  = region + ND;         // ND  [b*1024+key][128]
    unsigned short* Vtg = region + 2 * ND;     // ND  [b,h,d][1024 keys]
    unsigned short* Th  = region + 3 * ND;     // ND (attn out)
    unsigned short* Hh  = region;              // FFN hidden (4*ND), overlaps
    unsigned short* wt  = region + 4 * ND;     // 425984 bf16
    int* cnt     = (int*)(wt + 425984);        // N
    int* csr_off = cnt + N;                    // N+1
    int* cursor  = csr_off + N + 1;            // N
    int* csr_src = cursor + N;                 // E
    int* partial = csr_src + E;                // 128
    int* pbase   = partial + 128;              // 128

    // --- CSR + dinv (hierarchical scan) ---
    hipMemsetAsync(cnt, 0, (size_t)N * sizeof(int), stream);
    count_kernel<<<(E + 255) / 256, 256, 0, stream>>>(dstE, cnt, E);
    scanA_kernel<<<N / 256, 256, 0, stream>>>(cnt, partial);
    scanB_kernel<<<1, 128, 0, stream>>>(partial, pbase);
    scanC_kernel<<<N / 256, 256, 0, stream>>>(cnt, pbase, csr_off, cursor, dinv, N, E);
    place_kernel<<<(E + 255) / 256, 256, 0, stream>>>(srcE, dstE, cursor, csr_src, E);

    // --- converts + weight transpose ---
    conv_kernel<<<(int)(ND / 1024), 256, 0, stream>>>(xraw, xrawh);
    copyconv_kernel<<<(int)(ND / 1024), 256, 0, stream>>>(enc, bufY, bufYh);
    wtrans_kernel<<<dim3(256, 14), 256, 0, stream>>>(Wg1, Wg2, Wq, Wk, Wv, Wo, Wff1, Wff2, wt);

    // --- GCN layer 1 ---
    gemm64_kernel<<<dim3(N / 64, 2), 256, 0, stream>>>(xrawh, wt, hsh, nullptr, 128,
        nullptr, dinv, 0, 1);
    gather_kernel<<<N / 4, 256, 0, stream>>>(hsh, csr_off, csr_src, dinv, bg1, bufBh, N);
    // --- GCN layer 2 ---
    gemm64_kernel<<<dim3(N / 64, 2), 256, 0, stream>>>(bufBh, wt + 16384, hsh, nullptr, 128,
        nullptr, dinv, 0, 1);
    gather_kernel<<<N / 4, 256, 0, stream>>>(hsh, csr_off, csr_src, dinv, bg2, bufBh, N);
    // bufBh = GCN features (KV source)

    for (int l = 0; l < L; ++l) {
        const unsigned short* wtq  = wt + 32768  + (size_t)l * 16384;
        const unsigned short* wtkv = wt + 65536  + (size_t)l * 32768;
        const unsigned short* wto  = wt + 131072 + (size_t)l * 16384;
        const unsigned short* wtf1 = wt + 163840 + (size_t)l * 65536;
        const unsigned short* wtf2 = wt + 294912 + (size_t)l * 65536;

        gemm64_kernel<<<dim3(BM / 64, 2), 256, 0, stream>>>(bufYh, wtq, Qh, nullptr, 128,
            nullptr, nullptr, 0, 1);
        gemm64_kernel<<<dim3(N / 64, 4), 256, 0, stream>>>(bufBh, wtkv, Kg, Vtg, 128,
            nullptr, nullptr, 0, 2);

        attn_mfma_kernel<<<dim3(16, 8, B), 256, 0, stream>>>(Qh, Kg, Vtg, Th);

        // O-proj + residual + LN1 (fused)
        gemm_ln_kernel<<<BM / 64, 256, 0, stream>>>(Th, wto, 128, nullptr,
            bufY, bufY, bufYh, ln1g + l * 128, ln1b + l * 128);

        gemm64_kernel<<<dim3(BM / 64, 8), 256, 0, stream>>>(bufYh, wtf1, Hh, nullptr, 128,
            bff1 + l * 512, nullptr, 1, 1);

        // FFN2 + residual + LN2 (fused); final layer writes d_out directly
        float* rout = (l == L - 1) ? (float*)d_out : bufY;
        gemm_ln_kernel<<<BM / 64, 256, 0, stream>>>(Hh, wtf2, 512, bff2 + l * 128,
            bufY, rout, bufYh, ln2g + l * 128, ln2b + l * 128);
    }
}